// Round 9
// baseline (473.797 us; speedup 1.0000x reference)
//
#include <hip/hip_runtime.h>

#define N_NODES 50000
#define N_EDGES 1600000
#define R_REL 8
#define G_GRAPHS 64
#define D_INF 128
#define HIDF 128
#define CLSF 10

#define S_SEG (N_NODES * R_REL)   // 400000 (dst, rel) segments
#define RZ 9                      // 8 relations + root slice
#define PCHUNK 16                 // pool stage-1 chunks per graph

#define XG 8                      // XCD buckets
#define NODES_PER_G (N_NODES / XG)        // 6250
#define SEGS_PER_G (NODES_PER_G * R_REL)  // 50000 segments per bucket
#define CNT_INNER 128                     // blocks per bucket in cntb/scat

typedef __attribute__((ext_vector_type(8))) short short8;
typedef __attribute__((ext_vector_type(4))) float floatx4;
typedef __attribute__((ext_vector_type(2))) float f32x2;

typedef __attribute__((address_space(1))) const unsigned int guint;
typedef __attribute__((address_space(3))) unsigned int luint;
__device__ __forceinline__ void gload_lds16(const void* g, void* l) {
    // async global->LDS, 16 B/lane; LDS dest = wave-uniform base + lane*16
    __builtin_amdgcn_global_load_lds((guint*)g, (luint*)l, 16, 0, 0);
}

__device__ __forceinline__ unsigned short f2bf(float f) {
    unsigned int u = __float_as_uint(f);
    unsigned int r = (u + 0x7fffu + ((u >> 16) & 1u)) >> 16;   // RNE
    return (unsigned short)r;
}
// exact unpack of a packed bf16 pair (uint32) into two fp32
__device__ __forceinline__ float bflo(unsigned int u) { return __uint_as_float(u << 16); }
__device__ __forceinline__ float bfhi(unsigned int u) { return __uint_as_float(u & 0xffff0000u); }
// packed pair (lo,hi) -> f32x2 for v_pk_add_f32 accumulation
__device__ __forceinline__ f32x2 bfpair(unsigned int u) {
    return (f32x2){__uint_as_float(u << 16), __uint_as_float(u & 0xffff0000u)};
}

// ---------------- 8-bucket edge count (LDS-reduced, no scattered atomics) ----
__global__ __launch_bounds__(256) void bcnt_kernel(const int* __restrict__ dst,
                                                   int* __restrict__ bcnt) {
    __shared__ int lc[XG];
    if (threadIdx.x < XG) lc[threadIdx.x] = 0;
    __syncthreads();
    int i4 = blockIdx.x * 256 + threadIdx.x;
    if (i4 * 4 < N_EDGES) {
        int4 d = ((const int4*)dst)[i4];
        atomicAdd(&lc[d.x / NODES_PER_G], 1);
        atomicAdd(&lc[d.y / NODES_PER_G], 1);
        atomicAdd(&lc[d.z / NODES_PER_G], 1);
        atomicAdd(&lc[d.w / NODES_PER_G], 1);
    }
    __syncthreads();
    if (threadIdx.x < XG) atomicAdd(&bcnt[threadIdx.x], lc[threadIdx.x]);
}

// tiny scan over 8 bucket counts -> bases + partition cursors
__global__ void scan8_kernel(const int* __restrict__ bcnt,
                             int* __restrict__ bbase, int* __restrict__ bcur) {
    int s = 0;
    for (int b = 0; b < XG; b++) { bbase[b] = s; bcur[b] = s; s += bcnt[b]; }
    bbase[XG] = s;   // == N_EDGES
}

// ---------------- partition: seg computed inline, pairs into exact bucket region
// Per-wave LDS-aggregated reservations: only 8 global atomics per block.
__global__ __launch_bounds__(256) void part_kernel(const int* __restrict__ dst,
                                                   const int* __restrict__ et,
                                                   const int* __restrict__ src,
                                                   int* __restrict__ bcur,
                                                   int2* __restrict__ pairs) {
    __shared__ int lcnt[4][8], lbase[4][8], lpos[4][8];
    const int t = threadIdx.x, w = t >> 6;
    if (t < 32) { lcnt[t >> 3][t & 7] = 0; lpos[t >> 3][t & 7] = 0; }
    __syncthreads();
    const int base = blockIdx.x * 2048;
    int sg[8], sr[8];
#pragma unroll
    for (int q = 0; q < 2; q++) {
        int e0 = base + (q * 256 + t) * 4;
        if (e0 < N_EDGES) {
            int4 d4 = *(const int4*)(dst + e0);
            int4 t4 = *(const int4*)(et + e0);
            int4 r4 = *(const int4*)(src + e0);
            sg[q * 4 + 0] = d4.x * R_REL + t4.x; sg[q * 4 + 1] = d4.y * R_REL + t4.y;
            sg[q * 4 + 2] = d4.z * R_REL + t4.z; sg[q * 4 + 3] = d4.w * R_REL + t4.w;
            sr[q * 4 + 0] = r4.x; sr[q * 4 + 1] = r4.y;
            sr[q * 4 + 2] = r4.z; sr[q * 4 + 3] = r4.w;
        } else {
            sg[q * 4 + 0] = sg[q * 4 + 1] = sg[q * 4 + 2] = sg[q * 4 + 3] = -1;
        }
    }
#pragma unroll
    for (int j = 0; j < 8; j++)
        if (sg[j] >= 0) atomicAdd(&lcnt[w][sg[j] / SEGS_PER_G], 1);
    __syncthreads();
    if (t < 32) lbase[t >> 3][t & 7] = atomicAdd(&bcur[t & 7], lcnt[t >> 3][t & 7]);
    __syncthreads();
#pragma unroll
    for (int j = 0; j < 8; j++)
        if (sg[j] >= 0) {
            int b = sg[j] / SEGS_PER_G;
            int p = lbase[w][b] + atomicAdd(&lpos[w][b], 1);
            pairs[p] = make_int2(sg[j], sr[j]);
        }
}

// ---------------- per-segment count + rank, XCD-affine --------------------
// All traffic (pairs reads, cnt atomics, brank writes) stays in one XCD's L2.
// atomicAdd return value = stable within-segment rank (max seg count ~22 << 255).
__global__ __launch_bounds__(256) void cntb_kernel(const int2* __restrict__ pairs,
                                                   const int* __restrict__ bbase,
                                                   int* __restrict__ cnt,
                                                   unsigned char* __restrict__ brank) {
    int xg = blockIdx.x & (XG - 1);
    int inner = blockIdx.x >> 3;
    int bbeg = bbase[xg], bend = bbase[xg + 1];
    for (int i = bbeg + inner * 256 + threadIdx.x; i < bend; i += CNT_INNER * 256) {
        int2 v = pairs[i];
        brank[i] = (unsigned char)atomicAdd(&cnt[v.x], 1);
    }
}

// ---------------- scan over segment counts ----------------
#define SCAN_BLK 256
#define SCAN_ELEMS 1024
#define NB_SCAN ((S_SEG + SCAN_ELEMS - 1) / SCAN_ELEMS)   // 391

__global__ __launch_bounds__(SCAN_BLK) void scan1_kernel(const int* __restrict__ cnt,
                                                         int* __restrict__ off,
                                                         int* __restrict__ bsum) {
    __shared__ int sd[SCAN_BLK];
    int t = threadIdx.x;
    int base = blockIdx.x * SCAN_ELEMS + t * 4;
    int v[4];
    int tsum = 0;
#pragma unroll
    for (int j = 0; j < 4; j++) {
        v[j] = (base + j < S_SEG) ? cnt[base + j] : 0;
        tsum += v[j];
    }
    sd[t] = tsum;
    __syncthreads();
    for (int d = 1; d < SCAN_BLK; d <<= 1) {
        int x = (t >= d) ? sd[t - d] : 0;
        __syncthreads();
        sd[t] += x;
        __syncthreads();
    }
    int incl = sd[t];
    int run = incl - tsum;
#pragma unroll
    for (int j = 0; j < 4; j++) {
        if (base + j < S_SEG) off[base + j] = run;
        run += v[j];
    }
    if (t == SCAN_BLK - 1) bsum[blockIdx.x] = incl;
}

// fused: redundant per-block scan of the 391 block sums + absolute off.
__global__ __launch_bounds__(512) void absoff2_kernel(int* __restrict__ off,
                                                      const int* __restrict__ bsum) {
    __shared__ int sd[512];
    int t = threadIdx.x;
    int v = (t < NB_SCAN) ? bsum[t] : 0;
    sd[t] = v;
    __syncthreads();
    for (int d = 1; d < 512; d <<= 1) {
        int x = (t >= d) ? sd[t - d] : 0;
        __syncthreads();
        sd[t] += x;
        __syncthreads();
    }
    int pre = (blockIdx.x == 0) ? 0 : sd[blockIdx.x - 1];
    int base = blockIdx.x * SCAN_ELEMS + t * 2;
#pragma unroll
    for (int j = 0; j < 2; j++) {
        int i = base + j;
        if (i < S_SEG) off[i] += pre;
    }
}

// ---------------- scatter within bucket: XCD-affine, NO atomics --------------
// pos = off[sg] + brank[i]; esrc region for this bucket is XCD-local.
__global__ __launch_bounds__(256) void scat_kernel(const int2* __restrict__ pairs,
                                                   const int* __restrict__ bbase,
                                                   const unsigned char* __restrict__ brank,
                                                   const int* __restrict__ off,
                                                   unsigned short* __restrict__ esrc) {
    int xg = blockIdx.x & (XG - 1);
    int inner = blockIdx.x >> 3;
    int bbeg = bbase[xg], bend = bbase[xg + 1];
    for (int i = bbeg + inner * 256 + threadIdx.x; i < bend; i += CNT_INNER * 256) {
        int2 v = pairs[i];
        esrc[off[v.x] + brank[i]] = (unsigned short)v.y;
    }
}

// ---------------- convert x fp32 -> bf16 compact [N,128], float4 ------------
__global__ __launch_bounds__(256) void convx_kernel(const float* __restrict__ x,
                                                    unsigned short* __restrict__ xb) {
    int i4 = blockIdx.x * 256 + threadIdx.x;
    if (i4 * 4 < N_NODES * D_INF) {
        float4 v = ((const float4*)x)[i4];
        ushort4 o;
        o.x = f2bf(v.x); o.y = f2bf(v.y); o.z = f2bf(v.z); o.w = f2bf(v.w);
        ((ushort4*)xb)[i4] = o;
    }
}

// ---------------- build bf16 weights wz[9][128][128]: [r][col][k] ----------
__global__ __launch_bounds__(256) void convw9_kernel(const float* __restrict__ W,
                                                     const float* __restrict__ root,
                                                     unsigned short* __restrict__ wz) {
    __shared__ float t[16][17];
    int r = blockIdx.z;
    int k0 = blockIdx.x * 16, c0 = blockIdx.y * 16;
    int tx = threadIdx.x & 15, ty = threadIdx.x >> 4;
    const float* srcp = (r < 8) ? (W + (size_t)r * 128 * 128) : root;
    t[ty][tx] = srcp[(size_t)(k0 + ty) * 128 + c0 + tx];
    __syncthreads();
    wz[(size_t)r * 16384 + (size_t)(c0 + ty) * 128 + k0 + tx] = f2bf(t[tx][ty]);
}

// ---------------- segment mean: one 16-lane group per (dst,rel) segment ------
__global__ __launch_bounds__(256) void agg_mean(
    const unsigned short* __restrict__ hsrc,   // [N,128] bf16
    const unsigned short* __restrict__ esrc,   // src sorted by (dst,rel), 2B
    const int* __restrict__ off,               // [S_SEG] absolute starts
    unsigned short* __restrict__ m)            // [S_SEG][128] == [N][8][128]
{
    int sg = blockIdx.x * 16 + (threadIdx.x >> 4);
    int l = threadIdx.x & 15;                  // 16 lanes x 16B cover one 256B row
    int beg = off[sg];
    int end = (sg + 1 < S_SEG) ? off[sg + 1] : N_EDGES;
    float w = 1.0f / (float)max(end - beg, 1);

    f32x2 p0 = (f32x2){0.f, 0.f}, p1 = (f32x2){0.f, 0.f};
    f32x2 p2 = (f32x2){0.f, 0.f}, p3 = (f32x2){0.f, 0.f};
    int e = beg;
    for (; e + 4 <= end; e += 4) {
        int s0 = esrc[e], s1 = esrc[e + 1], s2 = esrc[e + 2], s3 = esrc[e + 3];
        uint4 v0 = *(const uint4*)(hsrc + (size_t)s0 * HIDF + l * 8);
        uint4 v1 = *(const uint4*)(hsrc + (size_t)s1 * HIDF + l * 8);
        uint4 v2 = *(const uint4*)(hsrc + (size_t)s2 * HIDF + l * 8);
        uint4 v3 = *(const uint4*)(hsrc + (size_t)s3 * HIDF + l * 8);
        p0 += bfpair(v0.x) + bfpair(v1.x) + bfpair(v2.x) + bfpair(v3.x);
        p1 += bfpair(v0.y) + bfpair(v1.y) + bfpair(v2.y) + bfpair(v3.y);
        p2 += bfpair(v0.z) + bfpair(v1.z) + bfpair(v2.z) + bfpair(v3.z);
        p3 += bfpair(v0.w) + bfpair(v1.w) + bfpair(v2.w) + bfpair(v3.w);
    }
    for (; e < end; e++) {
        int s0 = esrc[e];
        uint4 v0 = *(const uint4*)(hsrc + (size_t)s0 * HIDF + l * 8);
        p0 += bfpair(v0.x); p1 += bfpair(v0.y);
        p2 += bfpair(v0.z); p3 += bfpair(v0.w);
    }
    uint4 o;
    o.x = (unsigned int)f2bf(p0.x * w) | ((unsigned int)f2bf(p0.y * w) << 16);
    o.y = (unsigned int)f2bf(p1.x * w) | ((unsigned int)f2bf(p1.y * w) << 16);
    o.z = (unsigned int)f2bf(p2.x * w) | ((unsigned int)f2bf(p2.y * w) << 16);
    o.w = (unsigned int)f2bf(p3.x * w) | ((unsigned int)f2bf(p3.y * w) << 16);
    *(uint4*)(m + (size_t)sg * HIDF + l * 8) = o;
}

// ---------------- transform GEMM over K=1152: h = relu([m | hsrc] @ wz + b) ---
__global__ __launch_bounds__(256) void transform9(
    const unsigned short* __restrict__ mm,     // [N][8][128] bf16
    const unsigned short* __restrict__ hsrc,   // [N][128] bf16 (root operand)
    const unsigned short* __restrict__ wz,     // [9][128][128] bf16 [r][col][k]
    const float* __restrict__ bias,
    unsigned short* __restrict__ hout)         // [N][128] bf16
{
    __shared__ __align__(16) unsigned short A4[4][128][32];  // 32 KB
    __shared__ __align__(16) unsigned short B4[4][128][32];  // 32 KB

    const int tx = threadIdx.x;
    const int wave = tx >> 6, lane = tx & 63;
    const int quad = lane >> 4, lq = lane & 15;
    const int srow = lane >> 2, sch = lane & 3;
    const int row0 = blockIdx.x * 128;

    floatx4 acc[2][8];
#pragma unroll
    for (int i = 0; i < 2; i++)
#pragma unroll
        for (int j = 0; j < 8; j++) acc[i][j] = (floatx4){0.f, 0.f, 0.f, 0.f};

    for (int r = 0; r < RZ; r++) {
#pragma unroll
        for (int kk = 0; kk < 4; kk++) {
#pragma unroll
            for (int p = 0; p < 2; p++) {
                int rr = (wave * 2 + p) * 16;
                int gr = row0 + rr + srow; if (gr >= N_NODES) gr = N_NODES - 1;
                const unsigned short* ap = (r < 8)
                    ? mm + (size_t)gr * (R_REL * HIDF) + r * HIDF
                    : hsrc + (size_t)gr * HIDF;
                gload_lds16(ap + kk * 32 + sch * 8, &A4[kk][rr][0]);
                gload_lds16(wz + ((size_t)r * 128 + rr + srow) * 128 + kk * 32 + sch * 8,
                            &B4[kk][rr][0]);
            }
        }
        __syncthreads();

#pragma unroll
        for (int kk = 0; kk < 4; kk++) {
            short8 af[2], bfr[8];
#pragma unroll
            for (int i = 0; i < 2; i++)
                af[i] = *(const short8*)(&A4[kk][wave * 32 + i * 16 + lq][quad * 8]);
#pragma unroll
            for (int j = 0; j < 8; j++)
                bfr[j] = *(const short8*)(&B4[kk][j * 16 + lq][quad * 8]);
#pragma unroll
            for (int i = 0; i < 2; i++)
#pragma unroll
                for (int j = 0; j < 8; j++)
                    acc[i][j] = __builtin_amdgcn_mfma_f32_16x16x32_bf16(af[i], bfr[j], acc[i][j], 0, 0, 0);
        }
        __syncthreads();
    }

    // epilogue: bias + relu + bf16 pack (C/D layout col=lane&15, row=quad*4+reg)
#pragma unroll
    for (int i = 0; i < 2; i++)
#pragma unroll
        for (int j = 0; j < 8; j++) {
            int col = j * 16 + lq;
            float bv = bias[col];
#pragma unroll
            for (int rg = 0; rg < 4; rg++) {
                int row = row0 + wave * 32 + i * 16 + quad * 4 + rg;
                if (row < N_NODES)
                    hout[(size_t)row * HIDF + col] = f2bf(fmaxf(acc[i][j][rg] + bv, 0.f));
            }
        }
}

// ---------------- global mean pool, two-stage, no atomics ----------------
__global__ __launch_bounds__(256) void pool1_kernel(const unsigned short* __restrict__ h,
                                                    const int* __restrict__ batch,
                                                    float* __restrict__ partial) {  // [G][PCHUNK][128]
    int g = blockIdx.x;
    int p = blockIdx.y;
    int lo, hi;
    {
        int l = 0, r = N_NODES;
        while (l < r) { int m = (l + r) >> 1; if (batch[m] < g) l = m + 1; else r = m; }
        lo = l;
        l = lo; r = N_NODES;
        while (l < r) { int m = (l + r) >> 1; if (batch[m] < g + 1) l = m + 1; else r = m; }
        hi = l;
    }
    int t = threadIdx.x;
    int rowlane = t >> 5;
    int c4 = t & 31;
    float a0 = 0.f, a1 = 0.f, a2 = 0.f, a3 = 0.f;
    for (int n = lo + p + rowlane * PCHUNK; n < hi; n += 8 * PCHUNK) {
        uint2 v = *(const uint2*)(h + (size_t)n * HIDF + c4 * 4);
        a0 += bflo(v.x); a1 += bfhi(v.x); a2 += bflo(v.y); a3 += bfhi(v.y);
    }
    __shared__ float red[8][128];
    if (rowlane == 0) {
        red[0][c4 * 4 + 0] = a0; red[0][c4 * 4 + 1] = a1;
        red[0][c4 * 4 + 2] = a2; red[0][c4 * 4 + 3] = a3;
    }
    __syncthreads();
    for (int s = 1; s < 8; s++) {
        if (rowlane == s) {
            red[0][c4 * 4 + 0] += a0; red[0][c4 * 4 + 1] += a1;
            red[0][c4 * 4 + 2] += a2; red[0][c4 * 4 + 3] += a3;
        }
        __syncthreads();
    }
    if (t < 128) partial[((size_t)g * PCHUNK + p) * 128 + t] = red[0][t];
}

// fused pool stage-2 + final linear: one block per graph
__global__ __launch_bounds__(128) void poolfin_kernel(const float* __restrict__ partial,
                                                      const int* __restrict__ batch,
                                                      const float* __restrict__ lin_w,  // [128,10]
                                                      const float* __restrict__ lin_b,  // [10]
                                                      float* __restrict__ out) {        // [64,10]
    __shared__ float gl[HIDF];
    int g = blockIdx.x;
    int lo, hi;
    {
        int l = 0, r = N_NODES;
        while (l < r) { int m = (l + r) >> 1; if (batch[m] < g) l = m + 1; else r = m; }
        lo = l;
        l = lo; r = N_NODES;
        while (l < r) { int m = (l + r) >> 1; if (batch[m] < g + 1) l = m + 1; else r = m; }
        hi = l;
    }
    int t = threadIdx.x;
    float s = 0.f;
#pragma unroll
    for (int p = 0; p < PCHUNK; p++)
        s += partial[((size_t)g * PCHUNK + p) * 128 + t];
    gl[t] = s / (float)max(hi - lo, 1);
    __syncthreads();
    if (t < CLSF) {
        float acc = lin_b[t];
#pragma unroll 16
        for (int d = 0; d < HIDF; d++) acc += gl[d] * lin_w[d * CLSF + t];
        out[g * CLSF + t] = acc;
    }
}

extern "C" void kernel_launch(void* const* d_in, const int* in_sizes, int n_in,
                              void* d_out, int out_size, void* d_ws, size_t ws_size,
                              hipStream_t stream) {
    const float* x     = (const float*)d_in[0];
    const int*   ei    = (const int*)d_in[1];
    const int*   et    = (const int*)d_in[2];
    const int*   batch = (const int*)d_in[3];
    const float* W1    = (const float*)d_in[4];
    const float* root1 = (const float*)d_in[5];
    const float* b1    = (const float*)d_in[6];
    const float* W2    = (const float*)d_in[7];
    const float* root2 = (const float*)d_in[8];
    const float* b2    = (const float*)d_in[9];
    const float* lin_w = (const float*)d_in[10];
    const float* lin_b = (const float*)d_in[11];
    float* out = (float*)d_out;

    const int* src = ei;            // edge_index[0]
    const int* dst = ei + N_EDGES;  // edge_index[1]

    char* ws = (char*)d_ws;
    unsigned short* xb  = (unsigned short*)ws; ws += (size_t)N_NODES * HIDF * 2;   // 12.8 MB
    unsigned short* h1  = (unsigned short*)ws; ws += (size_t)N_NODES * HIDF * 2;   // 12.8 MB
    unsigned short* h2  = (unsigned short*)ws; ws += (size_t)N_NODES * HIDF * 2;   // 12.8 MB
    unsigned short* m   = (unsigned short*)ws; ws += (size_t)S_SEG * HIDF * 2;     // 102.4 MB
    unsigned short* wz1 = (unsigned short*)ws; ws += (size_t)RZ * 128 * 128 * 2;   // 288 KB
    unsigned short* wz2 = (unsigned short*)ws; ws += (size_t)RZ * 128 * 128 * 2;
    int*   cnt    = (int*)ws;   ws += (size_t)S_SEG * 4;
    int*   off    = (int*)ws;   ws += (size_t)S_SEG * 4;
    int*   bsum   = (int*)ws;   ws += 512 * 4;
    int2*  pairs  = (int2*)ws;  ws += (size_t)N_EDGES * 8;                          // 12.8 MB
    unsigned char*  brank = (unsigned char*)ws;  ws += (size_t)N_EDGES;             // 1.6 MB
    unsigned short* esrc  = (unsigned short*)ws; ws += (size_t)N_EDGES * 2;         // 3.2 MB
    int*   bcnt   = (int*)ws;   ws += 64 * 4;
    int*   bbase  = (int*)ws;   ws += 64 * 4;
    int*   bcur   = (int*)ws;   ws += 64 * 4;
    float* partial = (float*)ws; ws += (size_t)G_GRAPHS * PCHUNK * 128 * 4;

    hipMemsetAsync(cnt, 0, (size_t)S_SEG * 4, stream);
    hipMemsetAsync(bcnt, 0, 64 * 4, stream);

    // ---- counting sort: bucket-count -> exact partition -> XCD-local
    //      count+rank -> scan -> XCD-affine atomic-free scatter ----
    bcnt_kernel<<<(N_EDGES / 4 + 255) / 256, 256, 0, stream>>>(dst, bcnt);
    scan8_kernel<<<1, 1, 0, stream>>>(bcnt, bbase, bcur);
    part_kernel<<<(N_EDGES + 2047) / 2048, 256, 0, stream>>>(dst, et, src, bcur, pairs);
    cntb_kernel<<<XG * CNT_INNER, 256, 0, stream>>>(pairs, bbase, cnt, brank);
    scan1_kernel<<<NB_SCAN, SCAN_BLK, 0, stream>>>(cnt, off, bsum);
    absoff2_kernel<<<NB_SCAN, 512, 0, stream>>>(off, bsum);
    scat_kernel<<<XG * CNT_INNER, 256, 0, stream>>>(pairs, bbase, brank, off, esrc);

    // ---- bf16 conversions ----
    convx_kernel<<<(N_NODES * D_INF / 4 + 255) / 256, 256, 0, stream>>>(x, xb);
    convw9_kernel<<<dim3(8, 8, RZ), 256, 0, stream>>>(W1, root1, wz1);
    convw9_kernel<<<dim3(8, 8, RZ), 256, 0, stream>>>(W2, root2, wz2);

    const int NGB = (N_NODES + 127) / 128;   // 391
    const int NSB = S_SEG / 16;              // 25000

    // ---- layer 1: aggregate-first (parallel), then K=1152 GEMM ----
    agg_mean<<<NSB, 256, 0, stream>>>(xb, esrc, off, m);
    transform9<<<NGB, 256, 0, stream>>>(m, xb, wz1, b1, h1);

    // ---- layer 2 ----
    agg_mean<<<NSB, 256, 0, stream>>>(h1, esrc, off, m);
    transform9<<<NGB, 256, 0, stream>>>(m, h1, wz2, b2, h2);

    // ---- pool (two-stage, no atomics) + classify ----
    pool1_kernel<<<dim3(G_GRAPHS, PCHUNK), 256, 0, stream>>>(h2, batch, partial);
    poolfin_kernel<<<G_GRAPHS, 128, 0, stream>>>(partial, batch, lin_w, lin_b, out);

    (void)in_sizes; (void)n_in; (void)out_size; (void)ws_size;
}

// Round 10
// 471.886 us; speedup vs baseline: 1.0041x; 1.0041x over previous
//
#include <hip/hip_runtime.h>

#define N_NODES 50000
#define N_EDGES 1600000
#define R_REL 8
#define G_GRAPHS 64
#define D_INF 128
#define HIDF 128
#define CLSF 10

#define S_SEG (N_NODES * R_REL)   // 400000 (dst, rel) segments
#define RZ 9                      // 8 relations + root slice
#define PCHUNK 16                 // pool stage-1 chunks per graph

#define XG 8                      // XCD groups for partitioned count
#define NODES_PER_G (N_NODES / XG)        // 6250
#define SEGS_PER_G (NODES_PER_G * R_REL)  // 50000
#define SORT_BLKS_PER_G 256
#define SORT_GRID (XG * SORT_BLKS_PER_G)

typedef __attribute__((ext_vector_type(8))) short short8;
typedef __attribute__((ext_vector_type(4))) float floatx4;
typedef __attribute__((ext_vector_type(2))) float f32x2;

typedef __attribute__((address_space(1))) const unsigned int guint;
typedef __attribute__((address_space(3))) unsigned int luint;
__device__ __forceinline__ void gload_lds16(const void* g, void* l) {
    // async global->LDS, 16 B/lane; LDS dest = wave-uniform base + lane*16
    __builtin_amdgcn_global_load_lds((guint*)g, (luint*)l, 16, 0, 0);
}

__device__ __forceinline__ unsigned short f2bf(float f) {
    unsigned int u = __float_as_uint(f);
    unsigned int r = (u + 0x7fffu + ((u >> 16) & 1u)) >> 16;   // RNE
    return (unsigned short)r;
}
// exact unpack of a packed bf16 pair (uint32) into two fp32
__device__ __forceinline__ float bflo(unsigned int u) { return __uint_as_float(u << 16); }
__device__ __forceinline__ float bfhi(unsigned int u) { return __uint_as_float(u & 0xffff0000u); }
// packed pair (lo,hi) -> f32x2 for v_pk_add_f32 accumulation
__device__ __forceinline__ f32x2 bfpair(unsigned int u) {
    return (f32x2){__uint_as_float(u << 16), __uint_as_float(u & 0xffff0000u)};
}
// pack 4 f32x2 (scaled by w) into one bf16 short8 fragment
__device__ __forceinline__ short8 pack8(f32x2 a, f32x2 b, f32x2 c, f32x2 d, float w) {
    union { uint4 u; short8 s; } o;
    o.u.x = (unsigned int)f2bf(a.x * w) | ((unsigned int)f2bf(a.y * w) << 16);
    o.u.y = (unsigned int)f2bf(b.x * w) | ((unsigned int)f2bf(b.y * w) << 16);
    o.u.z = (unsigned int)f2bf(c.x * w) | ((unsigned int)f2bf(c.y * w) << 16);
    o.u.w = (unsigned int)f2bf(d.x * w) | ((unsigned int)f2bf(d.y * w) << 16);
    return o.s;
}

__device__ __forceinline__ int ntload(const int* p) { return __builtin_nontemporal_load(p); }

// ---------------- pack (dst, rel) -> segment id, one vectorized pass ---------
__global__ __launch_bounds__(256) void seg_kernel(const int* __restrict__ dst,
                                                  const int* __restrict__ et,
                                                  int* __restrict__ seg) {
    int i4 = blockIdx.x * 256 + threadIdx.x;
    if (i4 * 4 >= N_EDGES) return;
    int4 d = ((const int4*)dst)[i4];
    int4 t = ((const int4*)et)[i4];
    int4 s;
    s.x = d.x * R_REL + t.x; s.y = d.y * R_REL + t.y;
    s.z = d.z * R_REL + t.z; s.w = d.w * R_REL + t.w;
    ((int4*)seg)[i4] = s;
}

// ---------------- count + rank per (dst, rel) segment — XCD-partitioned -------
// 8 filter passes: XCD-local atomic targets. atomicAdd's return value IS the
// edge's stable rank within its segment -> no second atomic pass needed.
__global__ __launch_bounds__(256) void count_kernel(const int* __restrict__ seg,
                                                    int* __restrict__ cnt,
                                                    unsigned short* __restrict__ rank) {
    int xg = blockIdx.x & (XG - 1);
    int inner = blockIdx.x >> 3;
    int lo = xg * SEGS_PER_G, hi = lo + SEGS_PER_G;
    for (int e = inner * 256 + threadIdx.x; e < N_EDGES; e += SORT_BLKS_PER_G * 256) {
        int sg = ntload(seg + e);
        if (sg >= lo && sg < hi)
            rank[e] = (unsigned short)atomicAdd(&cnt[sg], 1);
    }
}

// ---------------- scan over segment counts ----------------
#define SCAN_BLK 256
#define SCAN_ELEMS 1024
#define NB_SCAN ((S_SEG + SCAN_ELEMS - 1) / SCAN_ELEMS)   // 391

__global__ __launch_bounds__(SCAN_BLK) void scan1_kernel(const int* __restrict__ cnt,
                                                         int* __restrict__ off,
                                                         int* __restrict__ bsum) {
    __shared__ int sd[SCAN_BLK];
    int t = threadIdx.x;
    int base = blockIdx.x * SCAN_ELEMS + t * 4;
    int v[4];
    int tsum = 0;
#pragma unroll
    for (int j = 0; j < 4; j++) {
        v[j] = (base + j < S_SEG) ? cnt[base + j] : 0;
        tsum += v[j];
    }
    sd[t] = tsum;
    __syncthreads();
    for (int d = 1; d < SCAN_BLK; d <<= 1) {
        int x = (t >= d) ? sd[t - d] : 0;
        __syncthreads();
        sd[t] += x;
        __syncthreads();
    }
    int incl = sd[t];
    int run = incl - tsum;
#pragma unroll
    for (int j = 0; j < 4; j++) {
        if (base + j < S_SEG) off[base + j] = run;
        run += v[j];
    }
    if (t == SCAN_BLK - 1) bsum[blockIdx.x] = incl;
}

// fused: redundant per-block scan of the 391 block sums + absolute off.
__global__ __launch_bounds__(512) void absoff2_kernel(int* __restrict__ off,
                                                      const int* __restrict__ bsum) {
    __shared__ int sd[512];
    int t = threadIdx.x;
    int v = (t < NB_SCAN) ? bsum[t] : 0;
    sd[t] = v;
    __syncthreads();
    for (int d = 1; d < 512; d <<= 1) {
        int x = (t >= d) ? sd[t - d] : 0;
        __syncthreads();
        sd[t] += x;
        __syncthreads();
    }
    int pre = (blockIdx.x == 0) ? 0 : sd[blockIdx.x - 1];
    int base = blockIdx.x * SCAN_ELEMS + t * 2;
#pragma unroll
    for (int j = 0; j < 2; j++) {
        int i = base + j;
        if (i < S_SEG) off[i] += pre;
    }
}

// ---------------- scatter: single pass, NO atomics (pos = off[sg] + rank) ----
__global__ __launch_bounds__(256) void scatter_kernel(const int* __restrict__ seg,
                                                      const int* __restrict__ src,
                                                      const unsigned short* __restrict__ rank,
                                                      const int* __restrict__ off,
                                                      unsigned short* __restrict__ esrc) {
    int i4 = blockIdx.x * 256 + threadIdx.x;
    if (i4 * 4 >= N_EDGES) return;
    int4 s4 = ((const int4*)seg)[i4];
    int4 r4 = ((const int4*)src)[i4];
    ushort4 k4 = ((const ushort4*)rank)[i4];
    esrc[off[s4.x] + k4.x] = (unsigned short)r4.x;
    esrc[off[s4.y] + k4.y] = (unsigned short)r4.y;
    esrc[off[s4.z] + k4.z] = (unsigned short)r4.z;
    esrc[off[s4.w] + k4.w] = (unsigned short)r4.w;
}

// ---------------- convert x fp32 -> bf16 compact [N,128], float4 ------------
__global__ __launch_bounds__(256) void convx_kernel(const float* __restrict__ x,
                                                    unsigned short* __restrict__ xb) {
    int i4 = blockIdx.x * 256 + threadIdx.x;
    if (i4 * 4 < N_NODES * D_INF) {
        float4 v = ((const float4*)x)[i4];
        ushort4 o;
        o.x = f2bf(v.x); o.y = f2bf(v.y); o.z = f2bf(v.z); o.w = f2bf(v.w);
        ((ushort4*)xb)[i4] = o;
    }
}

// ---------------- build bf16 weights wz[9][128][128]: [r][col][k] ----------
__global__ __launch_bounds__(256) void convw9_kernel(const float* __restrict__ W,
                                                     const float* __restrict__ root,
                                                     unsigned short* __restrict__ wz) {
    __shared__ float t[16][17];
    int r = blockIdx.z;
    int k0 = blockIdx.x * 16, c0 = blockIdx.y * 16;
    int tx = threadIdx.x & 15, ty = threadIdx.x >> 4;
    const float* srcp = (r < 8) ? (W + (size_t)r * 128 * 128) : root;
    t[ty][tx] = srcp[(size_t)(k0 + ty) * 128 + c0 + tx];
    __syncthreads();
    wz[(size_t)r * 16384 + (size_t)(c0 + ty) * 128 + k0 + tx] = f2bf(t[tx][ty]);
}

// ---------------- fused layer: register-gather means + MFMA, no m round-trip --
// 4 waves/block, each wave owns 16 nodes. MFMA A-fragment layout (lane(quad,lq)
// holds row lq, channels quad*8+kk*32) lets each lane gather-accumulate exactly
// its own fragment channels in registers: no LDS A-tile, no block-wide gather
// barrier (the R1/R6 occupancy killers). LDS = B slice only (32 KB). B staging
// is issued async BEFORE the gather, so its latency hides under it.
__global__ __launch_bounds__(256, 3) void fused_rt(
    const unsigned short* __restrict__ hsrc,   // [N,128] bf16
    const unsigned short* __restrict__ esrc,   // src sorted by (dst,rel), 2B
    const int* __restrict__ off,               // [S_SEG] absolute starts
    const unsigned short* __restrict__ wz,     // [9][128][128] bf16 [r][col][k]
    const float* __restrict__ bias,
    unsigned short* __restrict__ hout)         // [N,128] bf16
{
    __shared__ __align__(16) unsigned short B4[4][128][32];  // 32 KB W_r slice

    const int tx = threadIdx.x;
    const int wave = tx >> 6, lane = tx & 63;
    const int quad = lane >> 4, lq = lane & 15;
    const int srow = lane >> 2, sch = lane & 3;
    const int node0 = blockIdx.x * 64 + wave * 16;
    const bool wvalid = (node0 < N_NODES);     // 50000 % 16 == 0: whole wave valid
    const int node = node0 + lq;

    floatx4 acc[8];
#pragma unroll
    for (int j = 0; j < 8; j++) acc[j] = (floatx4){0.f, 0.f, 0.f, 0.f};

    for (int r = 0; r < RZ; r++) {
        // stage B slice r (async; latency hidden under the gather below)
#pragma unroll
        for (int kk = 0; kk < 4; kk++)
#pragma unroll
            for (int p = 0; p < 2; p++) {
                int rr = (wave * 2 + p) * 16;
                gload_lds16(wz + ((size_t)r * 128 + rr + srow) * 128 + kk * 32 + sch * 8,
                            &B4[kk][rr][0]);
            }

        short8 af[4];
        if (wvalid) {
            if (r < 8) {
                // gather-mean for (node, r): lane accumulates its own fragment
                int sg = node * R_REL + r;
                int beg = off[sg];
                int end = (sg + 1 < S_SEG) ? off[sg + 1] : N_EDGES;
                float w = 1.0f / (float)max(end - beg, 1);
                f32x2 pa[16];
#pragma unroll
                for (int i = 0; i < 16; i++) pa[i] = (f32x2){0.f, 0.f};
                const unsigned short* hq = hsrc + quad * 8;
                int e = beg;
                for (; e + 2 <= end; e += 2) {
                    int s0 = esrc[e], s1 = esrc[e + 1];
                    const unsigned short* r0 = hq + (size_t)s0 * HIDF;
                    const unsigned short* r1 = hq + (size_t)s1 * HIDF;
#pragma unroll
                    for (int kk = 0; kk < 4; kk++) {
                        uint4 v0 = *(const uint4*)(r0 + kk * 32);
                        uint4 v1 = *(const uint4*)(r1 + kk * 32);
                        pa[kk * 4 + 0] += bfpair(v0.x) + bfpair(v1.x);
                        pa[kk * 4 + 1] += bfpair(v0.y) + bfpair(v1.y);
                        pa[kk * 4 + 2] += bfpair(v0.z) + bfpair(v1.z);
                        pa[kk * 4 + 3] += bfpair(v0.w) + bfpair(v1.w);
                    }
                }
                if (e < end) {
                    int s0 = esrc[e];
                    const unsigned short* r0 = hq + (size_t)s0 * HIDF;
#pragma unroll
                    for (int kk = 0; kk < 4; kk++) {
                        uint4 v0 = *(const uint4*)(r0 + kk * 32);
                        pa[kk * 4 + 0] += bfpair(v0.x);
                        pa[kk * 4 + 1] += bfpair(v0.y);
                        pa[kk * 4 + 2] += bfpair(v0.z);
                        pa[kk * 4 + 3] += bfpair(v0.w);
                    }
                }
#pragma unroll
                for (int kk = 0; kk < 4; kk++)
                    af[kk] = pack8(pa[kk * 4 + 0], pa[kk * 4 + 1],
                                   pa[kk * 4 + 2], pa[kk * 4 + 3], w);
            } else {
                // root slice: A fragment straight from hsrc (bf16, L2-hot)
#pragma unroll
                for (int kk = 0; kk < 4; kk++)
                    af[kk] = *(const short8*)(hsrc + (size_t)node * HIDF + quad * 8 + kk * 32);
            }
        }
        __syncthreads();   // B4 ready (also fences previous MFMA reads)

        if (wvalid) {
#pragma unroll
            for (int kk = 0; kk < 4; kk++)
#pragma unroll
                for (int j = 0; j < 8; j++) {
                    short8 b = *(const short8*)(&B4[kk][j * 16 + lq][quad * 8]);
                    acc[j] = __builtin_amdgcn_mfma_f32_16x16x32_bf16(af[kk], b, acc[j], 0, 0, 0);
                }
        }
        __syncthreads();   // protect B4 from next r's staging
    }

    // epilogue: bias + relu + bf16 (C/D layout: col=lane&15, row=quad*4+reg)
    if (wvalid) {
#pragma unroll
        for (int j = 0; j < 8; j++) {
            int col = j * 16 + lq;
            float bv = bias[col];
#pragma unroll
            for (int rg = 0; rg < 4; rg++) {
                int row = node0 + quad * 4 + rg;
                hout[(size_t)row * HIDF + col] = f2bf(fmaxf(acc[j][rg] + bv, 0.f));
            }
        }
    }
}

// ---------------- global mean pool, two-stage, no atomics ----------------
__global__ __launch_bounds__(256) void pool1_kernel(const unsigned short* __restrict__ h,
                                                    const int* __restrict__ batch,
                                                    float* __restrict__ partial) {  // [G][PCHUNK][128]
    int g = blockIdx.x;
    int p = blockIdx.y;
    int lo, hi;
    {
        int l = 0, r = N_NODES;
        while (l < r) { int m = (l + r) >> 1; if (batch[m] < g) l = m + 1; else r = m; }
        lo = l;
        l = lo; r = N_NODES;
        while (l < r) { int m = (l + r) >> 1; if (batch[m] < g + 1) l = m + 1; else r = m; }
        hi = l;
    }
    int t = threadIdx.x;
    int rowlane = t >> 5;
    int c4 = t & 31;
    float a0 = 0.f, a1 = 0.f, a2 = 0.f, a3 = 0.f;
    for (int n = lo + p + rowlane * PCHUNK; n < hi; n += 8 * PCHUNK) {
        uint2 v = *(const uint2*)(h + (size_t)n * HIDF + c4 * 4);
        a0 += bflo(v.x); a1 += bfhi(v.x); a2 += bflo(v.y); a3 += bfhi(v.y);
    }
    __shared__ float red[8][128];
    if (rowlane == 0) {
        red[0][c4 * 4 + 0] = a0; red[0][c4 * 4 + 1] = a1;
        red[0][c4 * 4 + 2] = a2; red[0][c4 * 4 + 3] = a3;
    }
    __syncthreads();
    for (int s = 1; s < 8; s++) {
        if (rowlane == s) {
            red[0][c4 * 4 + 0] += a0; red[0][c4 * 4 + 1] += a1;
            red[0][c4 * 4 + 2] += a2; red[0][c4 * 4 + 3] += a3;
        }
        __syncthreads();
    }
    if (t < 128) partial[((size_t)g * PCHUNK + p) * 128 + t] = red[0][t];
}

// fused pool stage-2 + final linear: one block per graph
__global__ __launch_bounds__(128) void poolfin_kernel(const float* __restrict__ partial,
                                                      const int* __restrict__ batch,
                                                      const float* __restrict__ lin_w,  // [128,10]
                                                      const float* __restrict__ lin_b,  // [10]
                                                      float* __restrict__ out) {        // [64,10]
    __shared__ float gl[HIDF];
    int g = blockIdx.x;
    int lo, hi;
    {
        int l = 0, r = N_NODES;
        while (l < r) { int m = (l + r) >> 1; if (batch[m] < g) l = m + 1; else r = m; }
        lo = l;
        l = lo; r = N_NODES;
        while (l < r) { int m = (l + r) >> 1; if (batch[m] < g + 1) l = m + 1; else r = m; }
        hi = l;
    }
    int t = threadIdx.x;
    float s = 0.f;
#pragma unroll
    for (int p = 0; p < PCHUNK; p++)
        s += partial[((size_t)g * PCHUNK + p) * 128 + t];
    gl[t] = s / (float)max(hi - lo, 1);
    __syncthreads();
    if (t < CLSF) {
        float acc = lin_b[t];
#pragma unroll 16
        for (int d = 0; d < HIDF; d++) acc += gl[d] * lin_w[d * CLSF + t];
        out[g * CLSF + t] = acc;
    }
}

extern "C" void kernel_launch(void* const* d_in, const int* in_sizes, int n_in,
                              void* d_out, int out_size, void* d_ws, size_t ws_size,
                              hipStream_t stream) {
    const float* x     = (const float*)d_in[0];
    const int*   ei    = (const int*)d_in[1];
    const int*   et    = (const int*)d_in[2];
    const int*   batch = (const int*)d_in[3];
    const float* W1    = (const float*)d_in[4];
    const float* root1 = (const float*)d_in[5];
    const float* b1    = (const float*)d_in[6];
    const float* W2    = (const float*)d_in[7];
    const float* root2 = (const float*)d_in[8];
    const float* b2    = (const float*)d_in[9];
    const float* lin_w = (const float*)d_in[10];
    const float* lin_b = (const float*)d_in[11];
    float* out = (float*)d_out;

    const int* src = ei;            // edge_index[0]
    const int* dst = ei + N_EDGES;  // edge_index[1]

    char* ws = (char*)d_ws;
    unsigned short* xb  = (unsigned short*)ws; ws += (size_t)N_NODES * HIDF * 2;   // 12.8 MB
    unsigned short* h1  = (unsigned short*)ws; ws += (size_t)N_NODES * HIDF * 2;   // 12.8 MB
    unsigned short* h2  = (unsigned short*)ws; ws += (size_t)N_NODES * HIDF * 2;   // 12.8 MB
    unsigned short* wz1 = (unsigned short*)ws; ws += (size_t)RZ * 128 * 128 * 2;   // 288 KB
    unsigned short* wz2 = (unsigned short*)ws; ws += (size_t)RZ * 128 * 128 * 2;
    int*   seg    = (int*)ws;   ws += (size_t)N_EDGES * 4;                          // 6.4 MB
    int*   cnt    = (int*)ws;   ws += (size_t)S_SEG * 4;
    int*   off    = (int*)ws;   ws += (size_t)S_SEG * 4;
    int*   bsum   = (int*)ws;   ws += 512 * 4;
    unsigned short* rank = (unsigned short*)ws; ws += (size_t)N_EDGES * 2;          // 3.2 MB
    unsigned short* esrc = (unsigned short*)ws; ws += (size_t)N_EDGES * 2;          // 3.2 MB
    float* partial = (float*)ws; ws += (size_t)G_GRAPHS * PCHUNK * 128 * 4;

    hipMemsetAsync(cnt, 0, (size_t)S_SEG * 4, stream);

    // ---- counting sort (R8 structure, frozen): count(+rank) -> scan ->
    //      atomic-free scatter ----
    seg_kernel<<<(N_EDGES / 4 + 255) / 256, 256, 0, stream>>>(dst, et, seg);
    count_kernel<<<SORT_GRID, 256, 0, stream>>>(seg, cnt, rank);
    scan1_kernel<<<NB_SCAN, SCAN_BLK, 0, stream>>>(cnt, off, bsum);
    absoff2_kernel<<<NB_SCAN, 512, 0, stream>>>(off, bsum);
    scatter_kernel<<<(N_EDGES / 4 + 255) / 256, 256, 0, stream>>>(seg, src, rank, off, esrc);

    // ---- bf16 conversions ----
    convx_kernel<<<(N_NODES * D_INF / 4 + 255) / 256, 256, 0, stream>>>(x, xb);
    convw9_kernel<<<dim3(8, 8, RZ), 256, 0, stream>>>(W1, root1, wz1);
    convw9_kernel<<<dim3(8, 8, RZ), 256, 0, stream>>>(W2, root2, wz2);

    const int NFB = (N_NODES + 63) / 64;   // 782 blocks, 4 waves x 16 nodes

    // ---- fused layers: register-gather means + K=1152 MFMA (no m buffer) ----
    fused_rt<<<NFB, 256, 0, stream>>>(xb, esrc, off, wz1, b1, h1);
    fused_rt<<<NFB, 256, 0, stream>>>(h1, esrc, off, wz2, b2, h2);

    // ---- pool (two-stage, no atomics) + classify ----
    pool1_kernel<<<dim3(G_GRAPHS, PCHUNK), 256, 0, stream>>>(h2, batch, partial);
    poolfin_kernel<<<G_GRAPHS, 128, 0, stream>>>(partial, batch, lin_w, lin_b, out);

    (void)in_sizes; (void)n_in; (void)out_size; (void)ws_size;
}

// Round 11
// 421.587 us; speedup vs baseline: 1.1238x; 1.1193x over previous
//
#include <hip/hip_runtime.h>

#define N_NODES 50000
#define N_EDGES 1600000
#define R_REL 8
#define G_GRAPHS 64
#define D_INF 128
#define HIDF 128
#define CLSF 10

#define S_SEG (N_NODES * R_REL)   // 400000 (dst, rel) segments
#define RZ 9                      // 8 relations + root slice
#define PCHUNK 16                 // pool stage-1 chunks per graph

#define XG 8                      // XCD groups for partitioned count
#define NODES_PER_G (N_NODES / XG)        // 6250
#define SEGS_PER_G (NODES_PER_G * R_REL)  // 50000
#define SORT_BLKS_PER_G 256
#define SORT_GRID (XG * SORT_BLKS_PER_G)

#define E4 (N_EDGES / 4)                       // 400000 int4 edge records
#define SEG_BLOCKS ((E4 + 255) / 256)          // 1563
#define X4 (N_NODES * D_INF / 4)               // 1.6M float4
#define CONVX_BLOCKS ((X4 + 255) / 256)        // 6250

typedef __attribute__((ext_vector_type(8))) short short8;
typedef __attribute__((ext_vector_type(4))) float floatx4;
typedef __attribute__((ext_vector_type(2))) float f32x2;

typedef __attribute__((address_space(1))) const unsigned int guint;
typedef __attribute__((address_space(3))) unsigned int luint;
__device__ __forceinline__ void gload_lds16(const void* g, void* l) {
    // async global->LDS, 16 B/lane; LDS dest = wave-uniform base + lane*16
    __builtin_amdgcn_global_load_lds((guint*)g, (luint*)l, 16, 0, 0);
}

__device__ __forceinline__ unsigned short f2bf(float f) {
    unsigned int u = __float_as_uint(f);
    unsigned int r = (u + 0x7fffu + ((u >> 16) & 1u)) >> 16;   // RNE
    return (unsigned short)r;
}
// exact unpack of a packed bf16 pair (uint32) into two fp32
__device__ __forceinline__ float bflo(unsigned int u) { return __uint_as_float(u << 16); }
__device__ __forceinline__ float bfhi(unsigned int u) { return __uint_as_float(u & 0xffff0000u); }
// packed pair (lo,hi) -> f32x2 for v_pk_add_f32 accumulation
__device__ __forceinline__ f32x2 bfpair(unsigned int u) {
    return (f32x2){__uint_as_float(u << 16), __uint_as_float(u & 0xffff0000u)};
}

// ---------------- prep: seg packing + x->bf16, one merged launch -------------
__global__ __launch_bounds__(256) void prep_kernel(const int* __restrict__ dst,
                                                   const int* __restrict__ et,
                                                   int* __restrict__ seg,
                                                   const float* __restrict__ x,
                                                   unsigned short* __restrict__ xb) {
    int b = blockIdx.x;
    if (b < SEG_BLOCKS) {
        int i4 = b * 256 + threadIdx.x;
        if (i4 < E4) {
            int4 d = ((const int4*)dst)[i4];
            int4 t = ((const int4*)et)[i4];
            int4 s;
            s.x = d.x * R_REL + t.x; s.y = d.y * R_REL + t.y;
            s.z = d.z * R_REL + t.z; s.w = d.w * R_REL + t.w;
            ((int4*)seg)[i4] = s;
        }
    } else {
        int i4 = (b - SEG_BLOCKS) * 256 + threadIdx.x;
        if (i4 < X4) {
            float4 v = ((const float4*)x)[i4];
            ushort4 o;
            o.x = f2bf(v.x); o.y = f2bf(v.y); o.z = f2bf(v.z); o.w = f2bf(v.w);
            ((ushort4*)xb)[i4] = o;
        }
    }
}

// ---------------- count + rank per (dst, rel) segment — XCD-partitioned -------
// 8 filter passes, int4-vectorized: 4 independent atomic chains in flight per
// thread. atomicAdd's return value IS the edge's within-segment rank (u8:
// max segment count ~25 << 255 -> halves rank-line write amplification).
__global__ __launch_bounds__(256) void count_kernel(const int* __restrict__ seg,
                                                    int* __restrict__ cnt,
                                                    unsigned char* __restrict__ rank) {
    int xg = blockIdx.x & (XG - 1);
    int inner = blockIdx.x >> 3;
    int lo = xg * SEGS_PER_G, hi = lo + SEGS_PER_G;
    for (int i4 = inner * 256 + threadIdx.x; i4 < E4; i4 += SORT_BLKS_PER_G * 256) {
        int4 s = ((const int4*)seg)[i4];
        int e = i4 * 4;
        if (s.x >= lo && s.x < hi) rank[e + 0] = (unsigned char)atomicAdd(&cnt[s.x], 1);
        if (s.y >= lo && s.y < hi) rank[e + 1] = (unsigned char)atomicAdd(&cnt[s.y], 1);
        if (s.z >= lo && s.z < hi) rank[e + 2] = (unsigned char)atomicAdd(&cnt[s.z], 1);
        if (s.w >= lo && s.w < hi) rank[e + 3] = (unsigned char)atomicAdd(&cnt[s.w], 1);
    }
}

// ---------------- scan over segment counts ----------------
#define SCAN_BLK 256
#define SCAN_ELEMS 1024
#define NB_SCAN ((S_SEG + SCAN_ELEMS - 1) / SCAN_ELEMS)   // 391

__global__ __launch_bounds__(SCAN_BLK) void scan1_kernel(const int* __restrict__ cnt,
                                                         int* __restrict__ off,
                                                         int* __restrict__ bsum) {
    __shared__ int sd[SCAN_BLK];
    int t = threadIdx.x;
    int base = blockIdx.x * SCAN_ELEMS + t * 4;
    int v[4];
    int tsum = 0;
#pragma unroll
    for (int j = 0; j < 4; j++) {
        v[j] = (base + j < S_SEG) ? cnt[base + j] : 0;
        tsum += v[j];
    }
    sd[t] = tsum;
    __syncthreads();
    for (int d = 1; d < SCAN_BLK; d <<= 1) {
        int x = (t >= d) ? sd[t - d] : 0;
        __syncthreads();
        sd[t] += x;
        __syncthreads();
    }
    int incl = sd[t];
    int run = incl - tsum;
#pragma unroll
    for (int j = 0; j < 4; j++) {
        if (base + j < S_SEG) off[base + j] = run;
        run += v[j];
    }
    if (t == SCAN_BLK - 1) bsum[blockIdx.x] = incl;
}

// fused: redundant per-block scan of the 391 block sums + absolute off.
__global__ __launch_bounds__(512) void absoff2_kernel(int* __restrict__ off,
                                                      const int* __restrict__ bsum) {
    __shared__ int sd[512];
    int t = threadIdx.x;
    int v = (t < NB_SCAN) ? bsum[t] : 0;
    sd[t] = v;
    __syncthreads();
    for (int d = 1; d < 512; d <<= 1) {
        int x = (t >= d) ? sd[t - d] : 0;
        __syncthreads();
        sd[t] += x;
        __syncthreads();
    }
    int pre = (blockIdx.x == 0) ? 0 : sd[blockIdx.x - 1];
    int base = blockIdx.x * SCAN_ELEMS + t * 2;
#pragma unroll
    for (int j = 0; j < 2; j++) {
        int i = base + j;
        if (i < S_SEG) off[i] += pre;
    }
}

// ---------------- scatter: single pass, NO atomics (pos = off[sg] + rank) ----
__global__ __launch_bounds__(256) void scatter_kernel(const int* __restrict__ seg,
                                                      const int* __restrict__ src,
                                                      const unsigned char* __restrict__ rank,
                                                      const int* __restrict__ off,
                                                      unsigned short* __restrict__ esrc) {
    int i4 = blockIdx.x * 256 + threadIdx.x;
    if (i4 >= E4) return;
    int4 s4 = ((const int4*)seg)[i4];
    int4 r4 = ((const int4*)src)[i4];
    uchar4 k4 = ((const uchar4*)rank)[i4];
    esrc[off[s4.x] + k4.x] = (unsigned short)r4.x;
    esrc[off[s4.y] + k4.y] = (unsigned short)r4.y;
    esrc[off[s4.z] + k4.z] = (unsigned short)r4.z;
    esrc[off[s4.w] + k4.w] = (unsigned short)r4.w;
}

// ---------------- build bf16 weights wz[2][9][128][128]: [r][col][k] ---------
// one launch covers both layers: z = layer*9 + r
__global__ __launch_bounds__(256) void convw18_kernel(const float* __restrict__ W1,
                                                      const float* __restrict__ root1,
                                                      const float* __restrict__ W2,
                                                      const float* __restrict__ root2,
                                                      unsigned short* __restrict__ wz1,
                                                      unsigned short* __restrict__ wz2) {
    __shared__ float t[16][17];
    int z = blockIdx.z;
    int layer = z / RZ, r = z % RZ;
    const float* W    = layer ? W2 : W1;
    const float* root = layer ? root2 : root1;
    unsigned short* wz = layer ? wz2 : wz1;
    int k0 = blockIdx.x * 16, c0 = blockIdx.y * 16;
    int tx = threadIdx.x & 15, ty = threadIdx.x >> 4;
    const float* srcp = (r < 8) ? (W + (size_t)r * 128 * 128) : root;
    t[ty][tx] = srcp[(size_t)(k0 + ty) * 128 + c0 + tx];
    __syncthreads();
    wz[(size_t)r * 16384 + (size_t)(c0 + ty) * 128 + k0 + tx] = f2bf(t[tx][ty]);
}

// ---------------- segment mean: one 16-lane group per (dst,rel) segment ------
__global__ __launch_bounds__(256) void agg_mean(
    const unsigned short* __restrict__ hsrc,   // [N,128] bf16
    const unsigned short* __restrict__ esrc,   // src sorted by (dst,rel), 2B
    const int* __restrict__ off,               // [S_SEG] absolute starts
    unsigned short* __restrict__ m)            // [S_SEG][128] == [N][8][128]
{
    int sg = blockIdx.x * 16 + (threadIdx.x >> 4);
    int l = threadIdx.x & 15;                  // 16 lanes x 16B cover one 256B row
    int beg = off[sg];
    int end = (sg + 1 < S_SEG) ? off[sg + 1] : N_EDGES;
    float w = 1.0f / (float)max(end - beg, 1);

    f32x2 p0 = (f32x2){0.f, 0.f}, p1 = (f32x2){0.f, 0.f};
    f32x2 p2 = (f32x2){0.f, 0.f}, p3 = (f32x2){0.f, 0.f};
    int e = beg;
    for (; e + 4 <= end; e += 4) {
        int s0 = esrc[e], s1 = esrc[e + 1], s2 = esrc[e + 2], s3 = esrc[e + 3];
        uint4 v0 = *(const uint4*)(hsrc + (size_t)s0 * HIDF + l * 8);
        uint4 v1 = *(const uint4*)(hsrc + (size_t)s1 * HIDF + l * 8);
        uint4 v2 = *(const uint4*)(hsrc + (size_t)s2 * HIDF + l * 8);
        uint4 v3 = *(const uint4*)(hsrc + (size_t)s3 * HIDF + l * 8);
        p0 += bfpair(v0.x) + bfpair(v1.x) + bfpair(v2.x) + bfpair(v3.x);
        p1 += bfpair(v0.y) + bfpair(v1.y) + bfpair(v2.y) + bfpair(v3.y);
        p2 += bfpair(v0.z) + bfpair(v1.z) + bfpair(v2.z) + bfpair(v3.z);
        p3 += bfpair(v0.w) + bfpair(v1.w) + bfpair(v2.w) + bfpair(v3.w);
    }
    for (; e < end; e++) {
        int s0 = esrc[e];
        uint4 v0 = *(const uint4*)(hsrc + (size_t)s0 * HIDF + l * 8);
        p0 += bfpair(v0.x); p1 += bfpair(v0.y);
        p2 += bfpair(v0.z); p3 += bfpair(v0.w);
    }
    uint4 o;
    o.x = (unsigned int)f2bf(p0.x * w) | ((unsigned int)f2bf(p0.y * w) << 16);
    o.y = (unsigned int)f2bf(p1.x * w) | ((unsigned int)f2bf(p1.y * w) << 16);
    o.z = (unsigned int)f2bf(p2.x * w) | ((unsigned int)f2bf(p2.y * w) << 16);
    o.w = (unsigned int)f2bf(p3.x * w) | ((unsigned int)f2bf(p3.y * w) << 16);
    *(uint4*)(m + (size_t)sg * HIDF + l * 8) = o;
}

// ---------------- transform GEMM over K=1152: h = relu([m | hsrc] @ wz + b) ---
__global__ __launch_bounds__(256) void transform9(
    const unsigned short* __restrict__ mm,     // [N][8][128] bf16
    const unsigned short* __restrict__ hsrc,   // [N][128] bf16 (root operand)
    const unsigned short* __restrict__ wz,     // [9][128][128] bf16 [r][col][k]
    const float* __restrict__ bias,
    unsigned short* __restrict__ hout)         // [N][128] bf16
{
    __shared__ __align__(16) unsigned short A4[4][128][32];  // 32 KB
    __shared__ __align__(16) unsigned short B4[4][128][32];  // 32 KB

    const int tx = threadIdx.x;
    const int wave = tx >> 6, lane = tx & 63;
    const int quad = lane >> 4, lq = lane & 15;
    const int srow = lane >> 2, sch = lane & 3;
    const int row0 = blockIdx.x * 128;

    floatx4 acc[2][8];
#pragma unroll
    for (int i = 0; i < 2; i++)
#pragma unroll
        for (int j = 0; j < 8; j++) acc[i][j] = (floatx4){0.f, 0.f, 0.f, 0.f};

    for (int r = 0; r < RZ; r++) {
#pragma unroll
        for (int kk = 0; kk < 4; kk++) {
#pragma unroll
            for (int p = 0; p < 2; p++) {
                int rr = (wave * 2 + p) * 16;
                int gr = row0 + rr + srow; if (gr >= N_NODES) gr = N_NODES - 1;
                const unsigned short* ap = (r < 8)
                    ? mm + (size_t)gr * (R_REL * HIDF) + r * HIDF
                    : hsrc + (size_t)gr * HIDF;
                gload_lds16(ap + kk * 32 + sch * 8, &A4[kk][rr][0]);
                gload_lds16(wz + ((size_t)r * 128 + rr + srow) * 128 + kk * 32 + sch * 8,
                            &B4[kk][rr][0]);
            }
        }
        __syncthreads();

#pragma unroll
        for (int kk = 0; kk < 4; kk++) {
            short8 af[2], bfr[8];
#pragma unroll
            for (int i = 0; i < 2; i++)
                af[i] = *(const short8*)(&A4[kk][wave * 32 + i * 16 + lq][quad * 8]);
#pragma unroll
            for (int j = 0; j < 8; j++)
                bfr[j] = *(const short8*)(&B4[kk][j * 16 + lq][quad * 8]);
#pragma unroll
            for (int i = 0; i < 2; i++)
#pragma unroll
                for (int j = 0; j < 8; j++)
                    acc[i][j] = __builtin_amdgcn_mfma_f32_16x16x32_bf16(af[i], bfr[j], acc[i][j], 0, 0, 0);
        }
        __syncthreads();
    }

    // epilogue: bias + relu + bf16 pack (C/D layout col=lane&15, row=quad*4+reg)
#pragma unroll
    for (int i = 0; i < 2; i++)
#pragma unroll
        for (int j = 0; j < 8; j++) {
            int col = j * 16 + lq;
            float bv = bias[col];
#pragma unroll
            for (int rg = 0; rg < 4; rg++) {
                int row = row0 + wave * 32 + i * 16 + quad * 4 + rg;
                if (row < N_NODES)
                    hout[(size_t)row * HIDF + col] = f2bf(fmaxf(acc[i][j][rg] + bv, 0.f));
            }
        }
}

// ---------------- global mean pool, two-stage, no atomics ----------------
__global__ __launch_bounds__(256) void pool1_kernel(const unsigned short* __restrict__ h,
                                                    const int* __restrict__ batch,
                                                    float* __restrict__ partial) {  // [G][PCHUNK][128]
    int g = blockIdx.x;
    int p = blockIdx.y;
    int lo, hi;
    {
        int l = 0, r = N_NODES;
        while (l < r) { int m = (l + r) >> 1; if (batch[m] < g) l = m + 1; else r = m; }
        lo = l;
        l = lo; r = N_NODES;
        while (l < r) { int m = (l + r) >> 1; if (batch[m] < g + 1) l = m + 1; else r = m; }
        hi = l;
    }
    int t = threadIdx.x;
    int rowlane = t >> 5;
    int c4 = t & 31;
    float a0 = 0.f, a1 = 0.f, a2 = 0.f, a3 = 0.f;
    for (int n = lo + p + rowlane * PCHUNK; n < hi; n += 8 * PCHUNK) {
        uint2 v = *(const uint2*)(h + (size_t)n * HIDF + c4 * 4);
        a0 += bflo(v.x); a1 += bfhi(v.x); a2 += bflo(v.y); a3 += bfhi(v.y);
    }
    __shared__ float red[8][128];
    if (rowlane == 0) {
        red[0][c4 * 4 + 0] = a0; red[0][c4 * 4 + 1] = a1;
        red[0][c4 * 4 + 2] = a2; red[0][c4 * 4 + 3] = a3;
    }
    __syncthreads();
    for (int s = 1; s < 8; s++) {
        if (rowlane == s) {
            red[0][c4 * 4 + 0] += a0; red[0][c4 * 4 + 1] += a1;
            red[0][c4 * 4 + 2] += a2; red[0][c4 * 4 + 3] += a3;
        }
        __syncthreads();
    }
    if (t < 128) partial[((size_t)g * PCHUNK + p) * 128 + t] = red[0][t];
}

// fused pool stage-2 + final linear: one block per graph
__global__ __launch_bounds__(128) void poolfin_kernel(const float* __restrict__ partial,
                                                      const int* __restrict__ batch,
                                                      const float* __restrict__ lin_w,  // [128,10]
                                                      const float* __restrict__ lin_b,  // [10]
                                                      float* __restrict__ out) {        // [64,10]
    __shared__ float gl[HIDF];
    int g = blockIdx.x;
    int lo, hi;
    {
        int l = 0, r = N_NODES;
        while (l < r) { int m = (l + r) >> 1; if (batch[m] < g) l = m + 1; else r = m; }
        lo = l;
        l = lo; r = N_NODES;
        while (l < r) { int m = (l + r) >> 1; if (batch[m] < g + 1) l = m + 1; else r = m; }
        hi = l;
    }
    int t = threadIdx.x;
    float s = 0.f;
#pragma unroll
    for (int p = 0; p < PCHUNK; p++)
        s += partial[((size_t)g * PCHUNK + p) * 128 + t];
    gl[t] = s / (float)max(hi - lo, 1);
    __syncthreads();
    if (t < CLSF) {
        float acc = lin_b[t];
#pragma unroll 16
        for (int d = 0; d < HIDF; d++) acc += gl[d] * lin_w[d * CLSF + t];
        out[g * CLSF + t] = acc;
    }
}

extern "C" void kernel_launch(void* const* d_in, const int* in_sizes, int n_in,
                              void* d_out, int out_size, void* d_ws, size_t ws_size,
                              hipStream_t stream) {
    const float* x     = (const float*)d_in[0];
    const int*   ei    = (const int*)d_in[1];
    const int*   et    = (const int*)d_in[2];
    const int*   batch = (const int*)d_in[3];
    const float* W1    = (const float*)d_in[4];
    const float* root1 = (const float*)d_in[5];
    const float* b1    = (const float*)d_in[6];
    const float* W2    = (const float*)d_in[7];
    const float* root2 = (const float*)d_in[8];
    const float* b2    = (const float*)d_in[9];
    const float* lin_w = (const float*)d_in[10];
    const float* lin_b = (const float*)d_in[11];
    float* out = (float*)d_out;

    const int* src = ei;            // edge_index[0]
    const int* dst = ei + N_EDGES;  // edge_index[1]

    char* ws = (char*)d_ws;
    unsigned short* xb  = (unsigned short*)ws; ws += (size_t)N_NODES * HIDF * 2;   // 12.8 MB
    unsigned short* h1  = (unsigned short*)ws; ws += (size_t)N_NODES * HIDF * 2;   // 12.8 MB
    unsigned short* h2  = (unsigned short*)ws; ws += (size_t)N_NODES * HIDF * 2;   // 12.8 MB
    unsigned short* m   = (unsigned short*)ws; ws += (size_t)S_SEG * HIDF * 2;     // 102.4 MB
    unsigned short* wz1 = (unsigned short*)ws; ws += (size_t)RZ * 128 * 128 * 2;   // 288 KB
    unsigned short* wz2 = (unsigned short*)ws; ws += (size_t)RZ * 128 * 128 * 2;
    int*   seg    = (int*)ws;   ws += (size_t)N_EDGES * 4;                          // 6.4 MB
    int*   cnt    = (int*)ws;   ws += (size_t)S_SEG * 4;
    int*   off    = (int*)ws;   ws += (size_t)S_SEG * 4;
    int*   bsum   = (int*)ws;   ws += 512 * 4;
    unsigned char*  rank = (unsigned char*)ws;  ws += (size_t)N_EDGES;              // 1.6 MB
    unsigned short* esrc = (unsigned short*)ws; ws += (size_t)N_EDGES * 2;          // 3.2 MB
    float* partial = (float*)ws; ws += (size_t)G_GRAPHS * PCHUNK * 128 * 4;

    hipMemsetAsync(cnt, 0, (size_t)S_SEG * 4, stream);

    // ---- prep (seg pack + x->bf16) and weight conversion ----
    prep_kernel<<<SEG_BLOCKS + CONVX_BLOCKS, 256, 0, stream>>>(dst, et, seg, x, xb);
    convw18_kernel<<<dim3(8, 8, 2 * RZ), 256, 0, stream>>>(W1, root1, W2, root2, wz1, wz2);

    // ---- counting sort (R8 structure): count(+u8 rank) -> scan ->
    //      atomic-free scatter ----
    count_kernel<<<SORT_GRID, 256, 0, stream>>>(seg, cnt, rank);
    scan1_kernel<<<NB_SCAN, SCAN_BLK, 0, stream>>>(cnt, off, bsum);
    absoff2_kernel<<<NB_SCAN, 512, 0, stream>>>(off, bsum);
    scatter_kernel<<<SEG_BLOCKS, 256, 0, stream>>>(seg, src, rank, off, esrc);

    const int NGB = (N_NODES + 127) / 128;   // 391
    const int NSB = S_SEG / 16;              // 25000

    // ---- layer 1: aggregate-first (parallel), then K=1152 GEMM ----
    agg_mean<<<NSB, 256, 0, stream>>>(xb, esrc, off, m);
    transform9<<<NGB, 256, 0, stream>>>(m, xb, wz1, b1, h1);

    // ---- layer 2 ----
    agg_mean<<<NSB, 256, 0, stream>>>(h1, esrc, off, m);
    transform9<<<NGB, 256, 0, stream>>>(m, h1, wz2, b2, h2);

    // ---- pool (two-stage, no atomics) + classify ----
    pool1_kernel<<<dim3(G_GRAPHS, PCHUNK), 256, 0, stream>>>(h2, batch, partial);
    poolfin_kernel<<<G_GRAPHS, 128, 0, stream>>>(partial, batch, lin_w, lin_b, out);

    (void)in_sizes; (void)n_in; (void)out_size; (void)ws_size;
}

// Round 12
// 414.934 us; speedup vs baseline: 1.1419x; 1.0160x over previous
//
#include <hip/hip_runtime.h>

#define N_NODES 50000
#define N_EDGES 1600000
#define R_REL 8
#define G_GRAPHS 64
#define D_INF 128
#define HIDF 128
#define CLSF 10

#define S_SEG (N_NODES * R_REL)   // 400000 (dst, rel) segments
#define RZ 9                      // 8 relations + root slice
#define PCHUNK 16                 // pool stage-1 chunks per graph

#define XG 8                      // XCD groups for partitioned count
#define NODES_PER_G (N_NODES / XG)        // 6250
#define SEGS_PER_G (NODES_PER_G * R_REL)  // 50000
#define SORT_BLKS_PER_G 256
#define SORT_GRID (XG * SORT_BLKS_PER_G)
#define CNT_THREADS (SORT_BLKS_PER_G * 256)   // 65536 threads per XCD group

#define E4 (N_EDGES / 4)                       // 400000 int4 edge records
#define SEG_BLOCKS ((E4 + 255) / 256)          // 1563
#define X4 (N_NODES * D_INF / 4)               // 1.6M float4
#define CONVX_BLOCKS ((X4 + 255) / 256)        // 6250
#define C4Z (S_SEG / 4)                        // 100000 int4 of cnt
#define CNTZ_BLOCKS ((C4Z + 255) / 256)        // 391

typedef __attribute__((ext_vector_type(8))) short short8;
typedef __attribute__((ext_vector_type(4))) float floatx4;
typedef __attribute__((ext_vector_type(2))) float f32x2;

typedef __attribute__((address_space(1))) const unsigned int guint;
typedef __attribute__((address_space(3))) unsigned int luint;
__device__ __forceinline__ void gload_lds16(const void* g, void* l) {
    // async global->LDS, 16 B/lane; LDS dest = wave-uniform base + lane*16
    __builtin_amdgcn_global_load_lds((guint*)g, (luint*)l, 16, 0, 0);
}

__device__ __forceinline__ unsigned short f2bf(float f) {
    unsigned int u = __float_as_uint(f);
    unsigned int r = (u + 0x7fffu + ((u >> 16) & 1u)) >> 16;   // RNE
    return (unsigned short)r;
}
// exact unpack of a packed bf16 pair (uint32) into two fp32
__device__ __forceinline__ float bflo(unsigned int u) { return __uint_as_float(u << 16); }
__device__ __forceinline__ float bfhi(unsigned int u) { return __uint_as_float(u & 0xffff0000u); }
// packed pair (lo,hi) -> f32x2 for v_pk_add_f32 accumulation
__device__ __forceinline__ f32x2 bfpair(unsigned int u) {
    return (f32x2){__uint_as_float(u << 16), __uint_as_float(u & 0xffff0000u)};
}

// ---------------- prep: seg pack + x->bf16 + cnt zero, one merged launch -----
__global__ __launch_bounds__(256) void prep_kernel(const int* __restrict__ dst,
                                                   const int* __restrict__ et,
                                                   int* __restrict__ seg,
                                                   const float* __restrict__ x,
                                                   unsigned short* __restrict__ xb,
                                                   int* __restrict__ cnt) {
    int b = blockIdx.x;
    if (b < SEG_BLOCKS) {
        int i4 = b * 256 + threadIdx.x;
        if (i4 < E4) {
            int4 d = ((const int4*)dst)[i4];
            int4 t = ((const int4*)et)[i4];
            int4 s;
            s.x = d.x * R_REL + t.x; s.y = d.y * R_REL + t.y;
            s.z = d.z * R_REL + t.z; s.w = d.w * R_REL + t.w;
            ((int4*)seg)[i4] = s;
        }
    } else if (b < SEG_BLOCKS + CONVX_BLOCKS) {
        int i4 = (b - SEG_BLOCKS) * 256 + threadIdx.x;
        if (i4 < X4) {
            float4 v = ((const float4*)x)[i4];
            ushort4 o;
            o.x = f2bf(v.x); o.y = f2bf(v.y); o.z = f2bf(v.z); o.w = f2bf(v.w);
            ((ushort4*)xb)[i4] = o;
        }
    } else {
        int i4 = (b - SEG_BLOCKS - CONVX_BLOCKS) * 256 + threadIdx.x;
        if (i4 < C4Z) ((int4*)cnt)[i4] = make_int4(0, 0, 0, 0);
    }
}

// ---------------- count + rank per (dst, rel) segment — XCD-partitioned -------
// 8 filter passes. Two int4 batches per iteration -> up to 8 independent
// returned atomics in flight per thread (the kernel is atomic-RT latency
// bound: VALU 2.8%, occupancy 76%). rank u8 (max seg count ~25 << 255).
__global__ __launch_bounds__(256) void count_kernel(const int* __restrict__ seg,
                                                    int* __restrict__ cnt,
                                                    unsigned char* __restrict__ rank) {
    int xg = blockIdx.x & (XG - 1);
    int inner = blockIdx.x >> 3;
    int lo = xg * SEGS_PER_G, hi = lo + SEGS_PER_G;
    int tid = inner * 256 + threadIdx.x;            // 0 .. CNT_THREADS-1
    for (int i4 = tid; i4 < E4; i4 += 2 * CNT_THREADS) {
        int4 sa = ((const int4*)seg)[i4];
        int j4 = i4 + CNT_THREADS;
        int4 sb = (j4 < E4) ? ((const int4*)seg)[j4] : make_int4(-1, -1, -1, -1);
        int ea = i4 * 4, eb = j4 * 4;
        if (sa.x >= lo && sa.x < hi) rank[ea + 0] = (unsigned char)atomicAdd(&cnt[sa.x], 1);
        if (sa.y >= lo && sa.y < hi) rank[ea + 1] = (unsigned char)atomicAdd(&cnt[sa.y], 1);
        if (sa.z >= lo && sa.z < hi) rank[ea + 2] = (unsigned char)atomicAdd(&cnt[sa.z], 1);
        if (sa.w >= lo && sa.w < hi) rank[ea + 3] = (unsigned char)atomicAdd(&cnt[sa.w], 1);
        if (sb.x >= lo && sb.x < hi) rank[eb + 0] = (unsigned char)atomicAdd(&cnt[sb.x], 1);
        if (sb.y >= lo && sb.y < hi) rank[eb + 1] = (unsigned char)atomicAdd(&cnt[sb.y], 1);
        if (sb.z >= lo && sb.z < hi) rank[eb + 2] = (unsigned char)atomicAdd(&cnt[sb.z], 1);
        if (sb.w >= lo && sb.w < hi) rank[eb + 3] = (unsigned char)atomicAdd(&cnt[sb.w], 1);
    }
}

// ---------------- scan over segment counts ----------------
#define SCAN_BLK 256
#define SCAN_ELEMS 1024
#define NB_SCAN ((S_SEG + SCAN_ELEMS - 1) / SCAN_ELEMS)   // 391

__global__ __launch_bounds__(SCAN_BLK) void scan1_kernel(const int* __restrict__ cnt,
                                                         int* __restrict__ off,
                                                         int* __restrict__ bsum) {
    __shared__ int sd[SCAN_BLK];
    int t = threadIdx.x;
    int base = blockIdx.x * SCAN_ELEMS + t * 4;
    int v[4];
    int tsum = 0;
#pragma unroll
    for (int j = 0; j < 4; j++) {
        v[j] = (base + j < S_SEG) ? cnt[base + j] : 0;
        tsum += v[j];
    }
    sd[t] = tsum;
    __syncthreads();
    for (int d = 1; d < SCAN_BLK; d <<= 1) {
        int x = (t >= d) ? sd[t - d] : 0;
        __syncthreads();
        sd[t] += x;
        __syncthreads();
    }
    int incl = sd[t];
    int run = incl - tsum;
#pragma unroll
    for (int j = 0; j < 4; j++) {
        if (base + j < S_SEG) off[base + j] = run;
        run += v[j];
    }
    if (t == SCAN_BLK - 1) bsum[blockIdx.x] = incl;
}

// fused: redundant per-block scan of the 391 block sums + absolute off.
__global__ __launch_bounds__(512) void absoff2_kernel(int* __restrict__ off,
                                                      const int* __restrict__ bsum) {
    __shared__ int sd[512];
    int t = threadIdx.x;
    int v = (t < NB_SCAN) ? bsum[t] : 0;
    sd[t] = v;
    __syncthreads();
    for (int d = 1; d < 512; d <<= 1) {
        int x = (t >= d) ? sd[t - d] : 0;
        __syncthreads();
        sd[t] += x;
        __syncthreads();
    }
    int pre = (blockIdx.x == 0) ? 0 : sd[blockIdx.x - 1];
    int base = blockIdx.x * SCAN_ELEMS + t * 2;
#pragma unroll
    for (int j = 0; j < 2; j++) {
        int i = base + j;
        if (i < S_SEG) off[i] += pre;
    }
}

// ---------------- scatter: single pass, NO atomics (pos = off[sg] + rank) ----
__global__ __launch_bounds__(256) void scatter_kernel(const int* __restrict__ seg,
                                                      const int* __restrict__ src,
                                                      const unsigned char* __restrict__ rank,
                                                      const int* __restrict__ off,
                                                      unsigned short* __restrict__ esrc) {
    int i4 = blockIdx.x * 256 + threadIdx.x;
    if (i4 >= E4) return;
    int4 s4 = ((const int4*)seg)[i4];
    int4 r4 = ((const int4*)src)[i4];
    uchar4 k4 = ((const uchar4*)rank)[i4];
    esrc[off[s4.x] + k4.x] = (unsigned short)r4.x;
    esrc[off[s4.y] + k4.y] = (unsigned short)r4.y;
    esrc[off[s4.z] + k4.z] = (unsigned short)r4.z;
    esrc[off[s4.w] + k4.w] = (unsigned short)r4.w;
}

// ---------------- build bf16 weights wz[2][9][128][128]: [r][col][k] ---------
// one launch covers both layers: z = layer*9 + r
__global__ __launch_bounds__(256) void convw18_kernel(const float* __restrict__ W1,
                                                      const float* __restrict__ root1,
                                                      const float* __restrict__ W2,
                                                      const float* __restrict__ root2,
                                                      unsigned short* __restrict__ wz1,
                                                      unsigned short* __restrict__ wz2) {
    __shared__ float t[16][17];
    int z = blockIdx.z;
    int layer = z / RZ, r = z % RZ;
    const float* W    = layer ? W2 : W1;
    const float* root = layer ? root2 : root1;
    unsigned short* wz = layer ? wz2 : wz1;
    int k0 = blockIdx.x * 16, c0 = blockIdx.y * 16;
    int tx = threadIdx.x & 15, ty = threadIdx.x >> 4;
    const float* srcp = (r < 8) ? (W + (size_t)r * 128 * 128) : root;
    t[ty][tx] = srcp[(size_t)(k0 + ty) * 128 + c0 + tx];
    __syncthreads();
    wz[(size_t)r * 16384 + (size_t)(c0 + ty) * 128 + k0 + tx] = f2bf(t[tx][ty]);
}

// ---------------- segment mean: one 16-lane group per (dst,rel) segment ------
__global__ __launch_bounds__(256) void agg_mean(
    const unsigned short* __restrict__ hsrc,   // [N,128] bf16
    const unsigned short* __restrict__ esrc,   // src sorted by (dst,rel), 2B
    const int* __restrict__ off,               // [S_SEG] absolute starts
    unsigned short* __restrict__ m)            // [S_SEG][128] == [N][8][128]
{
    int sg = blockIdx.x * 16 + (threadIdx.x >> 4);
    int l = threadIdx.x & 15;                  // 16 lanes x 16B cover one 256B row
    int beg = off[sg];
    int end = (sg + 1 < S_SEG) ? off[sg + 1] : N_EDGES;
    float w = 1.0f / (float)max(end - beg, 1);

    f32x2 p0 = (f32x2){0.f, 0.f}, p1 = (f32x2){0.f, 0.f};
    f32x2 p2 = (f32x2){0.f, 0.f}, p3 = (f32x2){0.f, 0.f};
    int e = beg;
    for (; e + 4 <= end; e += 4) {
        int s0 = esrc[e], s1 = esrc[e + 1], s2 = esrc[e + 2], s3 = esrc[e + 3];
        uint4 v0 = *(const uint4*)(hsrc + (size_t)s0 * HIDF + l * 8);
        uint4 v1 = *(const uint4*)(hsrc + (size_t)s1 * HIDF + l * 8);
        uint4 v2 = *(const uint4*)(hsrc + (size_t)s2 * HIDF + l * 8);
        uint4 v3 = *(const uint4*)(hsrc + (size_t)s3 * HIDF + l * 8);
        p0 += bfpair(v0.x) + bfpair(v1.x) + bfpair(v2.x) + bfpair(v3.x);
        p1 += bfpair(v0.y) + bfpair(v1.y) + bfpair(v2.y) + bfpair(v3.y);
        p2 += bfpair(v0.z) + bfpair(v1.z) + bfpair(v2.z) + bfpair(v3.z);
        p3 += bfpair(v0.w) + bfpair(v1.w) + bfpair(v2.w) + bfpair(v3.w);
    }
    for (; e < end; e++) {
        int s0 = esrc[e];
        uint4 v0 = *(const uint4*)(hsrc + (size_t)s0 * HIDF + l * 8);
        p0 += bfpair(v0.x); p1 += bfpair(v0.y);
        p2 += bfpair(v0.z); p3 += bfpair(v0.w);
    }
    uint4 o;
    o.x = (unsigned int)f2bf(p0.x * w) | ((unsigned int)f2bf(p0.y * w) << 16);
    o.y = (unsigned int)f2bf(p1.x * w) | ((unsigned int)f2bf(p1.y * w) << 16);
    o.z = (unsigned int)f2bf(p2.x * w) | ((unsigned int)f2bf(p2.y * w) << 16);
    o.w = (unsigned int)f2bf(p3.x * w) | ((unsigned int)f2bf(p3.y * w) << 16);
    *(uint4*)(m + (size_t)sg * HIDF + l * 8) = o;
}

// ---------------- transform GEMM over K=1152: h = relu([m | hsrc] @ wz + b) ---
__global__ __launch_bounds__(256) void transform9(
    const unsigned short* __restrict__ mm,     // [N][8][128] bf16
    const unsigned short* __restrict__ hsrc,   // [N][128] bf16 (root operand)
    const unsigned short* __restrict__ wz,     // [9][128][128] bf16 [r][col][k]
    const float* __restrict__ bias,
    unsigned short* __restrict__ hout)         // [N][128] bf16
{
    __shared__ __align__(16) unsigned short A4[4][128][32];  // 32 KB
    __shared__ __align__(16) unsigned short B4[4][128][32];  // 32 KB

    const int tx = threadIdx.x;
    const int wave = tx >> 6, lane = tx & 63;
    const int quad = lane >> 4, lq = lane & 15;
    const int srow = lane >> 2, sch = lane & 3;
    const int row0 = blockIdx.x * 128;

    floatx4 acc[2][8];
#pragma unroll
    for (int i = 0; i < 2; i++)
#pragma unroll
        for (int j = 0; j < 8; j++) acc[i][j] = (floatx4){0.f, 0.f, 0.f, 0.f};

    for (int r = 0; r < RZ; r++) {
#pragma unroll
        for (int kk = 0; kk < 4; kk++) {
#pragma unroll
            for (int p = 0; p < 2; p++) {
                int rr = (wave * 2 + p) * 16;
                int gr = row0 + rr + srow; if (gr >= N_NODES) gr = N_NODES - 1;
                const unsigned short* ap = (r < 8)
                    ? mm + (size_t)gr * (R_REL * HIDF) + r * HIDF
                    : hsrc + (size_t)gr * HIDF;
                gload_lds16(ap + kk * 32 + sch * 8, &A4[kk][rr][0]);
                gload_lds16(wz + ((size_t)r * 128 + rr + srow) * 128 + kk * 32 + sch * 8,
                            &B4[kk][rr][0]);
            }
        }
        __syncthreads();

#pragma unroll
        for (int kk = 0; kk < 4; kk++) {
            short8 af[2], bfr[8];
#pragma unroll
            for (int i = 0; i < 2; i++)
                af[i] = *(const short8*)(&A4[kk][wave * 32 + i * 16 + lq][quad * 8]);
#pragma unroll
            for (int j = 0; j < 8; j++)
                bfr[j] = *(const short8*)(&B4[kk][j * 16 + lq][quad * 8]);
#pragma unroll
            for (int i = 0; i < 2; i++)
#pragma unroll
                for (int j = 0; j < 8; j++)
                    acc[i][j] = __builtin_amdgcn_mfma_f32_16x16x32_bf16(af[i], bfr[j], acc[i][j], 0, 0, 0);
        }
        __syncthreads();
    }

    // epilogue: bias + relu + bf16 pack (C/D layout col=lane&15, row=quad*4+reg)
#pragma unroll
    for (int i = 0; i < 2; i++)
#pragma unroll
        for (int j = 0; j < 8; j++) {
            int col = j * 16 + lq;
            float bv = bias[col];
#pragma unroll
            for (int rg = 0; rg < 4; rg++) {
                int row = row0 + wave * 32 + i * 16 + quad * 4 + rg;
                if (row < N_NODES)
                    hout[(size_t)row * HIDF + col] = f2bf(fmaxf(acc[i][j][rg] + bv, 0.f));
            }
        }
}

// ---------------- global mean pool, two-stage, no atomics ----------------
__global__ __launch_bounds__(256) void pool1_kernel(const unsigned short* __restrict__ h,
                                                    const int* __restrict__ batch,
                                                    float* __restrict__ partial) {  // [G][PCHUNK][128]
    int g = blockIdx.x;
    int p = blockIdx.y;
    int lo, hi;
    {
        int l = 0, r = N_NODES;
        while (l < r) { int m = (l + r) >> 1; if (batch[m] < g) l = m + 1; else r = m; }
        lo = l;
        l = lo; r = N_NODES;
        while (l < r) { int m = (l + r) >> 1; if (batch[m] < g + 1) l = m + 1; else r = m; }
        hi = l;
    }
    int t = threadIdx.x;
    int rowlane = t >> 5;
    int c4 = t & 31;
    float a0 = 0.f, a1 = 0.f, a2 = 0.f, a3 = 0.f;
    for (int n = lo + p + rowlane * PCHUNK; n < hi; n += 8 * PCHUNK) {
        uint2 v = *(const uint2*)(h + (size_t)n * HIDF + c4 * 4);
        a0 += bflo(v.x); a1 += bfhi(v.x); a2 += bflo(v.y); a3 += bfhi(v.y);
    }
    __shared__ float red[8][128];
    if (rowlane == 0) {
        red[0][c4 * 4 + 0] = a0; red[0][c4 * 4 + 1] = a1;
        red[0][c4 * 4 + 2] = a2; red[0][c4 * 4 + 3] = a3;
    }
    __syncthreads();
    for (int s = 1; s < 8; s++) {
        if (rowlane == s) {
            red[0][c4 * 4 + 0] += a0; red[0][c4 * 4 + 1] += a1;
            red[0][c4 * 4 + 2] += a2; red[0][c4 * 4 + 3] += a3;
        }
        __syncthreads();
    }
    if (t < 128) partial[((size_t)g * PCHUNK + p) * 128 + t] = red[0][t];
}

// fused pool stage-2 + final linear: one block per graph
__global__ __launch_bounds__(128) void poolfin_kernel(const float* __restrict__ partial,
                                                      const int* __restrict__ batch,
                                                      const float* __restrict__ lin_w,  // [128,10]
                                                      const float* __restrict__ lin_b,  // [10]
                                                      float* __restrict__ out) {        // [64,10]
    __shared__ float gl[HIDF];
    int g = blockIdx.x;
    int lo, hi;
    {
        int l = 0, r = N_NODES;
        while (l < r) { int m = (l + r) >> 1; if (batch[m] < g) l = m + 1; else r = m; }
        lo = l;
        l = lo; r = N_NODES;
        while (l < r) { int m = (l + r) >> 1; if (batch[m] < g + 1) l = m + 1; else r = m; }
        hi = l;
    }
    int t = threadIdx.x;
    float s = 0.f;
#pragma unroll
    for (int p = 0; p < PCHUNK; p++)
        s += partial[((size_t)g * PCHUNK + p) * 128 + t];
    gl[t] = s / (float)max(hi - lo, 1);
    __syncthreads();
    if (t < CLSF) {
        float acc = lin_b[t];
#pragma unroll 16
        for (int d = 0; d < HIDF; d++) acc += gl[d] * lin_w[d * CLSF + t];
        out[g * CLSF + t] = acc;
    }
}

extern "C" void kernel_launch(void* const* d_in, const int* in_sizes, int n_in,
                              void* d_out, int out_size, void* d_ws, size_t ws_size,
                              hipStream_t stream) {
    const float* x     = (const float*)d_in[0];
    const int*   ei    = (const int*)d_in[1];
    const int*   et    = (const int*)d_in[2];
    const int*   batch = (const int*)d_in[3];
    const float* W1    = (const float*)d_in[4];
    const float* root1 = (const float*)d_in[5];
    const float* b1    = (const float*)d_in[6];
    const float* W2    = (const float*)d_in[7];
    const float* root2 = (const float*)d_in[8];
    const float* b2    = (const float*)d_in[9];
    const float* lin_w = (const float*)d_in[10];
    const float* lin_b = (const float*)d_in[11];
    float* out = (float*)d_out;

    const int* src = ei;            // edge_index[0]
    const int* dst = ei + N_EDGES;  // edge_index[1]

    char* ws = (char*)d_ws;
    unsigned short* xb  = (unsigned short*)ws; ws += (size_t)N_NODES * HIDF * 2;   // 12.8 MB
    unsigned short* h1  = (unsigned short*)ws; ws += (size_t)N_NODES * HIDF * 2;   // 12.8 MB
    unsigned short* h2  = (unsigned short*)ws; ws += (size_t)N_NODES * HIDF * 2;   // 12.8 MB
    unsigned short* m   = (unsigned short*)ws; ws += (size_t)S_SEG * HIDF * 2;     // 102.4 MB
    unsigned short* wz1 = (unsigned short*)ws; ws += (size_t)RZ * 128 * 128 * 2;   // 288 KB
    unsigned short* wz2 = (unsigned short*)ws; ws += (size_t)RZ * 128 * 128 * 2;
    int*   seg    = (int*)ws;   ws += (size_t)N_EDGES * 4;                          // 6.4 MB
    int*   cnt    = (int*)ws;   ws += (size_t)S_SEG * 4;
    int*   off    = (int*)ws;   ws += (size_t)S_SEG * 4;
    int*   bsum   = (int*)ws;   ws += 512 * 4;
    unsigned char*  rank = (unsigned char*)ws;  ws += (size_t)N_EDGES;              // 1.6 MB
    unsigned short* esrc = (unsigned short*)ws; ws += (size_t)N_EDGES * 2;          // 3.2 MB
    float* partial = (float*)ws; ws += (size_t)G_GRAPHS * PCHUNK * 128 * 4;

    // ---- prep (seg pack + x->bf16 + cnt zero) and weight conversion ----
    prep_kernel<<<SEG_BLOCKS + CONVX_BLOCKS + CNTZ_BLOCKS, 256, 0, stream>>>(
        dst, et, seg, x, xb, cnt);
    convw18_kernel<<<dim3(8, 8, 2 * RZ), 256, 0, stream>>>(W1, root1, W2, root2, wz1, wz2);

    // ---- counting sort (R8 structure): count(+u8 rank, 2-deep ILP) -> scan ->
    //      atomic-free scatter ----
    count_kernel<<<SORT_GRID, 256, 0, stream>>>(seg, cnt, rank);
    scan1_kernel<<<NB_SCAN, SCAN_BLK, 0, stream>>>(cnt, off, bsum);
    absoff2_kernel<<<NB_SCAN, 512, 0, stream>>>(off, bsum);
    scatter_kernel<<<SEG_BLOCKS, 256, 0, stream>>>(seg, src, rank, off, esrc);

    const int NGB = (N_NODES + 127) / 128;   // 391
    const int NSB = S_SEG / 16;              // 25000

    // ---- layer 1: aggregate-first (parallel), then K=1152 GEMM ----
    agg_mean<<<NSB, 256, 0, stream>>>(xb, esrc, off, m);
    transform9<<<NGB, 256, 0, stream>>>(m, xb, wz1, b1, h1);

    // ---- layer 2 ----
    agg_mean<<<NSB, 256, 0, stream>>>(h1, esrc, off, m);
    transform9<<<NGB, 256, 0, stream>>>(m, h1, wz2, b2, h2);

    // ---- pool (two-stage, no atomics) + classify ----
    pool1_kernel<<<dim3(G_GRAPHS, PCHUNK), 256, 0, stream>>>(h2, batch, partial);
    poolfin_kernel<<<G_GRAPHS, 128, 0, stream>>>(partial, batch, lin_w, lin_b, out);

    (void)in_sizes; (void)n_in; (void)out_size; (void)ws_size;
}

// Round 13
// 410.916 us; speedup vs baseline: 1.1530x; 1.0098x over previous
//
#include <hip/hip_runtime.h>

#define N_NODES 50000
#define N_EDGES 1600000
#define R_REL 8
#define G_GRAPHS 64
#define D_INF 128
#define HIDF 128
#define CLSF 10

#define S_SEG (N_NODES * R_REL)   // 400000 (dst, rel) segments
#define RZ 9                      // 8 relations + root slice
#define PCHUNK 16                 // pool stage-1 chunks per graph

#define XG 8                      // XCD groups for partitioned count
#define NODES_PER_G (N_NODES / XG)        // 6250
#define SEGS_PER_G (NODES_PER_G * R_REL)  // 50000
#define SORT_BLKS_PER_G 256
#define SORT_GRID (XG * SORT_BLKS_PER_G)

#define E4 (N_EDGES / 4)                       // 400000 int4 edge records
#define SEG_BLOCKS ((E4 + 255) / 256)          // 1563
#define X4 (N_NODES * D_INF / 4)               // 1.6M float4
#define CONVX_BLOCKS ((X4 + 255) / 256)        // 6250
#define C4Z (S_SEG / 4)                        // 100000 int4 of cnt
#define CNTZ_BLOCKS ((C4Z + 255) / 256)        // 391
#define CONVW_BLOCKS (2 * RZ * 64)             // 1152: 18 slices x 64 16x16 tiles

typedef __attribute__((ext_vector_type(8))) short short8;
typedef __attribute__((ext_vector_type(4))) float floatx4;
typedef __attribute__((ext_vector_type(2))) float f32x2;

typedef __attribute__((address_space(1))) const unsigned int guint;
typedef __attribute__((address_space(3))) unsigned int luint;
__device__ __forceinline__ void gload_lds16(const void* g, void* l) {
    // async global->LDS, 16 B/lane; LDS dest = wave-uniform base + lane*16
    __builtin_amdgcn_global_load_lds((guint*)g, (luint*)l, 16, 0, 0);
}

__device__ __forceinline__ unsigned short f2bf(float f) {
    unsigned int u = __float_as_uint(f);
    unsigned int r = (u + 0x7fffu + ((u >> 16) & 1u)) >> 16;   // RNE
    return (unsigned short)r;
}
// exact unpack of a packed bf16 pair (uint32) into two fp32
__device__ __forceinline__ float bflo(unsigned int u) { return __uint_as_float(u << 16); }
__device__ __forceinline__ float bfhi(unsigned int u) { return __uint_as_float(u & 0xffff0000u); }
// packed pair (lo,hi) -> f32x2 for v_pk_add_f32 accumulation
__device__ __forceinline__ f32x2 bfpair(unsigned int u) {
    return (f32x2){__uint_as_float(u << 16), __uint_as_float(u & 0xffff0000u)};
}

// ---------------- prep: seg pack + x->bf16 + cnt zero + weight conversion ----
// one merged launch, four block ranges (each block takes exactly one branch)
__global__ __launch_bounds__(256) void prep_kernel(const int* __restrict__ dst,
                                                   const int* __restrict__ et,
                                                   int* __restrict__ seg,
                                                   const float* __restrict__ x,
                                                   unsigned short* __restrict__ xb,
                                                   int* __restrict__ cnt,
                                                   const float* __restrict__ W1,
                                                   const float* __restrict__ root1,
                                                   const float* __restrict__ W2,
                                                   const float* __restrict__ root2,
                                                   unsigned short* __restrict__ wz1,
                                                   unsigned short* __restrict__ wz2) {
    __shared__ float t[16][17];
    int b = blockIdx.x;
    if (b < SEG_BLOCKS) {
        int i4 = b * 256 + threadIdx.x;
        if (i4 < E4) {
            int4 d = ((const int4*)dst)[i4];
            int4 tt = ((const int4*)et)[i4];
            int4 s;
            s.x = d.x * R_REL + tt.x; s.y = d.y * R_REL + tt.y;
            s.z = d.z * R_REL + tt.z; s.w = d.w * R_REL + tt.w;
            ((int4*)seg)[i4] = s;
        }
    } else if (b < SEG_BLOCKS + CONVX_BLOCKS) {
        int i4 = (b - SEG_BLOCKS) * 256 + threadIdx.x;
        if (i4 < X4) {
            float4 v = ((const float4*)x)[i4];
            ushort4 o;
            o.x = f2bf(v.x); o.y = f2bf(v.y); o.z = f2bf(v.z); o.w = f2bf(v.w);
            ((ushort4*)xb)[i4] = o;
        }
    } else if (b < SEG_BLOCKS + CONVX_BLOCKS + CNTZ_BLOCKS) {
        int i4 = (b - SEG_BLOCKS - CONVX_BLOCKS) * 256 + threadIdx.x;
        if (i4 < C4Z) ((int4*)cnt)[i4] = make_int4(0, 0, 0, 0);
    } else {
        // weight conversion: wz[layer][r][col][k] = bf16(W[r][k][col])
        int b2 = b - SEG_BLOCKS - CONVX_BLOCKS - CNTZ_BLOCKS;   // 0..1151
        int z = b2 >> 6, tile = b2 & 63;
        int layer = z / RZ, r = z % RZ;
        const float* W    = layer ? W2 : W1;
        const float* root = layer ? root2 : root1;
        unsigned short* wz = layer ? wz2 : wz1;
        int k0 = (tile & 7) * 16, c0 = (tile >> 3) * 16;
        int tx = threadIdx.x & 15, ty = threadIdx.x >> 4;
        const float* srcp = (r < 8) ? (W + (size_t)r * 128 * 128) : root;
        t[ty][tx] = srcp[(size_t)(k0 + ty) * 128 + c0 + tx];
        __syncthreads();
        wz[(size_t)r * 16384 + (size_t)(c0 + ty) * 128 + k0 + tx] = f2bf(t[tx][ty]);
    }
}

// ---------------- count + rank per (dst, rel) segment — XCD-partitioned -------
// 8 filter passes, int4-vectorized (R11 form — measured optimum; 2-deep ILP
// variant regressed). atomicAdd's return value IS the edge's within-segment
// rank (u8: max seg count ~25 << 255). At the L2 atomic-RT floor.
__global__ __launch_bounds__(256) void count_kernel(const int* __restrict__ seg,
                                                    int* __restrict__ cnt,
                                                    unsigned char* __restrict__ rank) {
    int xg = blockIdx.x & (XG - 1);
    int inner = blockIdx.x >> 3;
    int lo = xg * SEGS_PER_G, hi = lo + SEGS_PER_G;
    for (int i4 = inner * 256 + threadIdx.x; i4 < E4; i4 += SORT_BLKS_PER_G * 256) {
        int4 s = ((const int4*)seg)[i4];
        int e = i4 * 4;
        if (s.x >= lo && s.x < hi) rank[e + 0] = (unsigned char)atomicAdd(&cnt[s.x], 1);
        if (s.y >= lo && s.y < hi) rank[e + 1] = (unsigned char)atomicAdd(&cnt[s.y], 1);
        if (s.z >= lo && s.z < hi) rank[e + 2] = (unsigned char)atomicAdd(&cnt[s.z], 1);
        if (s.w >= lo && s.w < hi) rank[e + 3] = (unsigned char)atomicAdd(&cnt[s.w], 1);
    }
}

// ---------------- scan over segment counts ----------------
#define SCAN_BLK 256
#define SCAN_ELEMS 1024
#define NB_SCAN ((S_SEG + SCAN_ELEMS - 1) / SCAN_ELEMS)   // 391

__global__ __launch_bounds__(SCAN_BLK) void scan1_kernel(const int* __restrict__ cnt,
                                                         int* __restrict__ off,
                                                         int* __restrict__ bsum) {
    __shared__ int sd[SCAN_BLK];
    int t = threadIdx.x;
    int base = blockIdx.x * SCAN_ELEMS + t * 4;
    int v[4];
    int tsum = 0;
#pragma unroll
    for (int j = 0; j < 4; j++) {
        v[j] = (base + j < S_SEG) ? cnt[base + j] : 0;
        tsum += v[j];
    }
    sd[t] = tsum;
    __syncthreads();
    for (int d = 1; d < SCAN_BLK; d <<= 1) {
        int x = (t >= d) ? sd[t - d] : 0;
        __syncthreads();
        sd[t] += x;
        __syncthreads();
    }
    int incl = sd[t];
    int run = incl - tsum;
#pragma unroll
    for (int j = 0; j < 4; j++) {
        if (base + j < S_SEG) off[base + j] = run;
        run += v[j];
    }
    if (t == SCAN_BLK - 1) bsum[blockIdx.x] = incl;
}

// fused: redundant per-block scan of the 391 block sums + absolute off.
__global__ __launch_bounds__(512) void absoff2_kernel(int* __restrict__ off,
                                                      const int* __restrict__ bsum) {
    __shared__ int sd[512];
    int t = threadIdx.x;
    int v = (t < NB_SCAN) ? bsum[t] : 0;
    sd[t] = v;
    __syncthreads();
    for (int d = 1; d < 512; d <<= 1) {
        int x = (t >= d) ? sd[t - d] : 0;
        __syncthreads();
        sd[t] += x;
        __syncthreads();
    }
    int pre = (blockIdx.x == 0) ? 0 : sd[blockIdx.x - 1];
    int base = blockIdx.x * SCAN_ELEMS + t * 2;
#pragma unroll
    for (int j = 0; j < 2; j++) {
        int i = base + j;
        if (i < S_SEG) off[i] += pre;
    }
}

// ---------------- scatter: single pass, NO atomics (pos = off[sg] + rank) ----
__global__ __launch_bounds__(256) void scatter_kernel(const int* __restrict__ seg,
                                                      const int* __restrict__ src,
                                                      const unsigned char* __restrict__ rank,
                                                      const int* __restrict__ off,
                                                      unsigned short* __restrict__ esrc) {
    int i4 = blockIdx.x * 256 + threadIdx.x;
    if (i4 >= E4) return;
    int4 s4 = ((const int4*)seg)[i4];
    int4 r4 = ((const int4*)src)[i4];
    uchar4 k4 = ((const uchar4*)rank)[i4];
    esrc[off[s4.x] + k4.x] = (unsigned short)r4.x;
    esrc[off[s4.y] + k4.y] = (unsigned short)r4.y;
    esrc[off[s4.z] + k4.z] = (unsigned short)r4.z;
    esrc[off[s4.w] + k4.w] = (unsigned short)r4.w;
}

// ---------------- segment mean: one 16-lane group per (dst,rel) segment ------
__global__ __launch_bounds__(256) void agg_mean(
    const unsigned short* __restrict__ hsrc,   // [N,128] bf16
    const unsigned short* __restrict__ esrc,   // src sorted by (dst,rel), 2B
    const int* __restrict__ off,               // [S_SEG] absolute starts
    unsigned short* __restrict__ m)            // [S_SEG][128] == [N][8][128]
{
    int sg = blockIdx.x * 16 + (threadIdx.x >> 4);
    int l = threadIdx.x & 15;                  // 16 lanes x 16B cover one 256B row
    int beg = off[sg];
    int end = (sg + 1 < S_SEG) ? off[sg + 1] : N_EDGES;
    float w = 1.0f / (float)max(end - beg, 1);

    f32x2 p0 = (f32x2){0.f, 0.f}, p1 = (f32x2){0.f, 0.f};
    f32x2 p2 = (f32x2){0.f, 0.f}, p3 = (f32x2){0.f, 0.f};
    int e = beg;
    for (; e + 4 <= end; e += 4) {
        int s0 = esrc[e], s1 = esrc[e + 1], s2 = esrc[e + 2], s3 = esrc[e + 3];
        uint4 v0 = *(const uint4*)(hsrc + (size_t)s0 * HIDF + l * 8);
        uint4 v1 = *(const uint4*)(hsrc + (size_t)s1 * HIDF + l * 8);
        uint4 v2 = *(const uint4*)(hsrc + (size_t)s2 * HIDF + l * 8);
        uint4 v3 = *(const uint4*)(hsrc + (size_t)s3 * HIDF + l * 8);
        p0 += bfpair(v0.x) + bfpair(v1.x) + bfpair(v2.x) + bfpair(v3.x);
        p1 += bfpair(v0.y) + bfpair(v1.y) + bfpair(v2.y) + bfpair(v3.y);
        p2 += bfpair(v0.z) + bfpair(v1.z) + bfpair(v2.z) + bfpair(v3.z);
        p3 += bfpair(v0.w) + bfpair(v1.w) + bfpair(v2.w) + bfpair(v3.w);
    }
    for (; e < end; e++) {
        int s0 = esrc[e];
        uint4 v0 = *(const uint4*)(hsrc + (size_t)s0 * HIDF + l * 8);
        p0 += bfpair(v0.x); p1 += bfpair(v0.y);
        p2 += bfpair(v0.z); p3 += bfpair(v0.w);
    }
    uint4 o;
    o.x = (unsigned int)f2bf(p0.x * w) | ((unsigned int)f2bf(p0.y * w) << 16);
    o.y = (unsigned int)f2bf(p1.x * w) | ((unsigned int)f2bf(p1.y * w) << 16);
    o.z = (unsigned int)f2bf(p2.x * w) | ((unsigned int)f2bf(p2.y * w) << 16);
    o.w = (unsigned int)f2bf(p3.x * w) | ((unsigned int)f2bf(p3.y * w) << 16);
    *(uint4*)(m + (size_t)sg * HIDF + l * 8) = o;
}

// ---------------- transform GEMM over K=1152: h = relu([m | hsrc] @ wz + b) ---
__global__ __launch_bounds__(256) void transform9(
    const unsigned short* __restrict__ mm,     // [N][8][128] bf16
    const unsigned short* __restrict__ hsrc,   // [N][128] bf16 (root operand)
    const unsigned short* __restrict__ wz,     // [9][128][128] bf16 [r][col][k]
    const float* __restrict__ bias,
    unsigned short* __restrict__ hout)         // [N][128] bf16
{
    __shared__ __align__(16) unsigned short A4[4][128][32];  // 32 KB
    __shared__ __align__(16) unsigned short B4[4][128][32];  // 32 KB

    const int tx = threadIdx.x;
    const int wave = tx >> 6, lane = tx & 63;
    const int quad = lane >> 4, lq = lane & 15;
    const int srow = lane >> 2, sch = lane & 3;
    const int row0 = blockIdx.x * 128;

    floatx4 acc[2][8];
#pragma unroll
    for (int i = 0; i < 2; i++)
#pragma unroll
        for (int j = 0; j < 8; j++) acc[i][j] = (floatx4){0.f, 0.f, 0.f, 0.f};

    for (int r = 0; r < RZ; r++) {
#pragma unroll
        for (int kk = 0; kk < 4; kk++) {
#pragma unroll
            for (int p = 0; p < 2; p++) {
                int rr = (wave * 2 + p) * 16;
                int gr = row0 + rr + srow; if (gr >= N_NODES) gr = N_NODES - 1;
                const unsigned short* ap = (r < 8)
                    ? mm + (size_t)gr * (R_REL * HIDF) + r * HIDF
                    : hsrc + (size_t)gr * HIDF;
                gload_lds16(ap + kk * 32 + sch * 8, &A4[kk][rr][0]);
                gload_lds16(wz + ((size_t)r * 128 + rr + srow) * 128 + kk * 32 + sch * 8,
                            &B4[kk][rr][0]);
            }
        }
        __syncthreads();

#pragma unroll
        for (int kk = 0; kk < 4; kk++) {
            short8 af[2], bfr[8];
#pragma unroll
            for (int i = 0; i < 2; i++)
                af[i] = *(const short8*)(&A4[kk][wave * 32 + i * 16 + lq][quad * 8]);
#pragma unroll
            for (int j = 0; j < 8; j++)
                bfr[j] = *(const short8*)(&B4[kk][j * 16 + lq][quad * 8]);
#pragma unroll
            for (int i = 0; i < 2; i++)
#pragma unroll
                for (int j = 0; j < 8; j++)
                    acc[i][j] = __builtin_amdgcn_mfma_f32_16x16x32_bf16(af[i], bfr[j], acc[i][j], 0, 0, 0);
        }
        __syncthreads();
    }

    // epilogue: bias + relu + bf16 pack (C/D layout col=lane&15, row=quad*4+reg)
#pragma unroll
    for (int i = 0; i < 2; i++)
#pragma unroll
        for (int j = 0; j < 8; j++) {
            int col = j * 16 + lq;
            float bv = bias[col];
#pragma unroll
            for (int rg = 0; rg < 4; rg++) {
                int row = row0 + wave * 32 + i * 16 + quad * 4 + rg;
                if (row < N_NODES)
                    hout[(size_t)row * HIDF + col] = f2bf(fmaxf(acc[i][j][rg] + bv, 0.f));
            }
        }
}

// ---------------- global mean pool, two-stage, no atomics ----------------
__global__ __launch_bounds__(256) void pool1_kernel(const unsigned short* __restrict__ h,
                                                    const int* __restrict__ batch,
                                                    float* __restrict__ partial) {  // [G][PCHUNK][128]
    int g = blockIdx.x;
    int p = blockIdx.y;
    int lo, hi;
    {
        int l = 0, r = N_NODES;
        while (l < r) { int m = (l + r) >> 1; if (batch[m] < g) l = m + 1; else r = m; }
        lo = l;
        l = lo; r = N_NODES;
        while (l < r) { int m = (l + r) >> 1; if (batch[m] < g + 1) l = m + 1; else r = m; }
        hi = l;
    }
    int t = threadIdx.x;
    int rowlane = t >> 5;
    int c4 = t & 31;
    float a0 = 0.f, a1 = 0.f, a2 = 0.f, a3 = 0.f;
    for (int n = lo + p + rowlane * PCHUNK; n < hi; n += 8 * PCHUNK) {
        uint2 v = *(const uint2*)(h + (size_t)n * HIDF + c4 * 4);
        a0 += bflo(v.x); a1 += bfhi(v.x); a2 += bflo(v.y); a3 += bfhi(v.y);
    }
    __shared__ float red[8][128];
    if (rowlane == 0) {
        red[0][c4 * 4 + 0] = a0; red[0][c4 * 4 + 1] = a1;
        red[0][c4 * 4 + 2] = a2; red[0][c4 * 4 + 3] = a3;
    }
    __syncthreads();
    for (int s = 1; s < 8; s++) {
        if (rowlane == s) {
            red[0][c4 * 4 + 0] += a0; red[0][c4 * 4 + 1] += a1;
            red[0][c4 * 4 + 2] += a2; red[0][c4 * 4 + 3] += a3;
        }
        __syncthreads();
    }
    if (t < 128) partial[((size_t)g * PCHUNK + p) * 128 + t] = red[0][t];
}

// fused pool stage-2 + final linear: one block per graph
__global__ __launch_bounds__(128) void poolfin_kernel(const float* __restrict__ partial,
                                                      const int* __restrict__ batch,
                                                      const float* __restrict__ lin_w,  // [128,10]
                                                      const float* __restrict__ lin_b,  // [10]
                                                      float* __restrict__ out) {        // [64,10]
    __shared__ float gl[HIDF];
    int g = blockIdx.x;
    int lo, hi;
    {
        int l = 0, r = N_NODES;
        while (l < r) { int m = (l + r) >> 1; if (batch[m] < g) l = m + 1; else r = m; }
        lo = l;
        l = lo; r = N_NODES;
        while (l < r) { int m = (l + r) >> 1; if (batch[m] < g + 1) l = m + 1; else r = m; }
        hi = l;
    }
    int t = threadIdx.x;
    float s = 0.f;
#pragma unroll
    for (int p = 0; p < PCHUNK; p++)
        s += partial[((size_t)g * PCHUNK + p) * 128 + t];
    gl[t] = s / (float)max(hi - lo, 1);
    __syncthreads();
    if (t < CLSF) {
        float acc = lin_b[t];
#pragma unroll 16
        for (int d = 0; d < HIDF; d++) acc += gl[d] * lin_w[d * CLSF + t];
        out[g * CLSF + t] = acc;
    }
}

extern "C" void kernel_launch(void* const* d_in, const int* in_sizes, int n_in,
                              void* d_out, int out_size, void* d_ws, size_t ws_size,
                              hipStream_t stream) {
    const float* x     = (const float*)d_in[0];
    const int*   ei    = (const int*)d_in[1];
    const int*   et    = (const int*)d_in[2];
    const int*   batch = (const int*)d_in[3];
    const float* W1    = (const float*)d_in[4];
    const float* root1 = (const float*)d_in[5];
    const float* b1    = (const float*)d_in[6];
    const float* W2    = (const float*)d_in[7];
    const float* root2 = (const float*)d_in[8];
    const float* b2    = (const float*)d_in[9];
    const float* lin_w = (const float*)d_in[10];
    const float* lin_b = (const float*)d_in[11];
    float* out = (float*)d_out;

    const int* src = ei;            // edge_index[0]
    const int* dst = ei + N_EDGES;  // edge_index[1]

    char* ws = (char*)d_ws;
    unsigned short* xb  = (unsigned short*)ws; ws += (size_t)N_NODES * HIDF * 2;   // 12.8 MB
    unsigned short* h1  = (unsigned short*)ws; ws += (size_t)N_NODES * HIDF * 2;   // 12.8 MB
    unsigned short* h2  = (unsigned short*)ws; ws += (size_t)N_NODES * HIDF * 2;   // 12.8 MB
    unsigned short* m   = (unsigned short*)ws; ws += (size_t)S_SEG * HIDF * 2;     // 102.4 MB
    unsigned short* wz1 = (unsigned short*)ws; ws += (size_t)RZ * 128 * 128 * 2;   // 288 KB
    unsigned short* wz2 = (unsigned short*)ws; ws += (size_t)RZ * 128 * 128 * 2;
    int*   seg    = (int*)ws;   ws += (size_t)N_EDGES * 4;                          // 6.4 MB
    int*   cnt    = (int*)ws;   ws += (size_t)S_SEG * 4;
    int*   off    = (int*)ws;   ws += (size_t)S_SEG * 4;
    int*   bsum   = (int*)ws;   ws += 512 * 4;
    unsigned char*  rank = (unsigned char*)ws;  ws += (size_t)N_EDGES;              // 1.6 MB
    unsigned short* esrc = (unsigned short*)ws; ws += (size_t)N_EDGES * 2;          // 3.2 MB
    float* partial = (float*)ws; ws += (size_t)G_GRAPHS * PCHUNK * 128 * 4;

    // ---- prep: seg pack + x->bf16 + cnt zero + weight conversion (1 launch) --
    prep_kernel<<<SEG_BLOCKS + CONVX_BLOCKS + CNTZ_BLOCKS + CONVW_BLOCKS, 256, 0, stream>>>(
        dst, et, seg, x, xb, cnt, W1, root1, W2, root2, wz1, wz2);

    // ---- counting sort (R8/R11 structure, frozen): count(+u8 rank) -> scan ->
    //      atomic-free scatter ----
    count_kernel<<<SORT_GRID, 256, 0, stream>>>(seg, cnt, rank);
    scan1_kernel<<<NB_SCAN, SCAN_BLK, 0, stream>>>(cnt, off, bsum);
    absoff2_kernel<<<NB_SCAN, 512, 0, stream>>>(off, bsum);
    scatter_kernel<<<SEG_BLOCKS, 256, 0, stream>>>(seg, src, rank, off, esrc);

    const int NGB = (N_NODES + 127) / 128;   // 391
    const int NSB = S_SEG / 16;              // 25000

    // ---- layer 1: aggregate-first (parallel), then K=1152 GEMM ----
    agg_mean<<<NSB, 256, 0, stream>>>(xb, esrc, off, m);
    transform9<<<NGB, 256, 0, stream>>>(m, xb, wz1, b1, h1);

    // ---- layer 2 ----
    agg_mean<<<NSB, 256, 0, stream>>>(h1, esrc, off, m);
    transform9<<<NGB, 256, 0, stream>>>(m, h1, wz2, b2, h2);

    // ---- pool (two-stage, no atomics) + classify ----
    pool1_kernel<<<dim3(G_GRAPHS, PCHUNK), 256, 0, stream>>>(h2, batch, partial);
    poolfin_kernel<<<G_GRAPHS, 128, 0, stream>>>(partial, batch, lin_w, lin_b, out);

    (void)in_sizes; (void)n_in; (void)out_size; (void)ws_size;
}